// Round 7
// baseline (335.959 us; speedup 1.0000x reference)
//
#include <hip/hip_runtime.h>
#include <hip/hip_bf16.h>

typedef __hip_bfloat16 bf16;
typedef __attribute__((ext_vector_type(8))) short short8;
typedef __attribute__((ext_vector_type(4))) float f32x4;

#define LOG2E 1.4426950408889634f

typedef const __attribute__((address_space(1))) void* gptr_t;
typedef __attribute__((address_space(3))) void* sptr_t;

__device__ __forceinline__ void async16(void* lds, const void* g) {
  __builtin_amdgcn_global_load_lds((gptr_t)g, (sptr_t)lds, 16, 0, 0);
}

__device__ __forceinline__ float bf2f(unsigned short u) {
  union { unsigned int i; float f; } c; c.i = ((unsigned int)u) << 16; return c.f;
}

// ---------------- merged prep: cast x + concat bias + 6 transposes ----------------

__global__ __launch_bounds__(256) void prep_all(
    const float* __restrict__ x, const float* __restrict__ bq,
    const float* __restrict__ bk, const float* __restrict__ bv,
    const float* __restrict__ wq, const float* __restrict__ wk,
    const float* __restrict__ wv, const float* __restrict__ wo,
    const float* __restrict__ w1, const float* __restrict__ w2,
    bf16* __restrict__ xb, float* __restrict__ bqkv,
    bf16* __restrict__ dqkv, bf16* __restrict__ dwo,
    bf16* __restrict__ dw1, bf16* __restrict__ dw2) {
  const int bid = blockIdx.x;
  if (bid < 4096) {
    int i = (bid * 256 + threadIdx.x) * 4;
    float4 v = *(const float4*)(x + i);
    bf16 h4[4] = {__float2bfloat16(v.x), __float2bfloat16(v.y),
                  __float2bfloat16(v.z), __float2bfloat16(v.w)};
    *(uint2*)((unsigned short*)xb + i) = *(uint2*)h4;
    return;
  }
  if (bid == 16384) {
#pragma unroll
    for (int j = 0; j < 12; ++j) {
      int i = j * 256 + threadIdx.x;
      bqkv[i] = (i < 1024) ? bq[i] : (i < 2048 ? bk[i - 1024] : bv[i - 2048]);
    }
    return;
  }
  __shared__ float tl[32][33];
  const int tid = bid - 4096;
  const float* s;
  bf16* d;
  int NN, KK, n0, k0;
  if (tid < 4096) {
    int m = tid >> 10, tile = tid & 1023;
    s = m == 0 ? wq : m == 1 ? wk : m == 2 ? wv : wo;
    d = m < 3 ? dqkv + (size_t)m * 1024 * 1024 : dwo;
    NN = 1024; KK = 1024;
    n0 = (tile & 31) * 32; k0 = (tile >> 5) * 32;
  } else if (tid < 8192) {
    int tile = tid - 4096;
    s = w1; d = dw1; NN = 4096; KK = 1024;
    n0 = (tile & 127) * 32; k0 = (tile >> 7) * 32;
  } else {
    int tile = tid - 8192;
    s = w2; d = dw2; NN = 1024; KK = 4096;
    n0 = (tile & 31) * 32; k0 = (tile >> 5) * 32;
  }
  const int tx = threadIdx.x & 31, ty = threadIdx.x >> 5;
#pragma unroll
  for (int j = 0; j < 4; ++j)
    tl[ty + j * 8][tx] = s[(size_t)(k0 + ty + j * 8) * NN + n0 + tx];
  __syncthreads();
#pragma unroll
  for (int j = 0; j < 4; ++j)
    d[(size_t)(n0 + ty + j * 8) * KK + k0 + tx] =
        __float2bfloat16(tl[tx][ty + j * 8]);
}

// ---------------- GEMM: C[M][N] = A[M][K] * Bt[N][K]^T + bias ----------------
// BK=32 double-buffer (32 KB LDS total), ONE barrier per K-tile, 4 blocks/CU.
// blockIdx.x = M-tile (32 tiles, 32%8==0) => all blocks reading A-slab m land
// on XCD m%8 -> one L2 copy of A. VT: V-columns also stored transposed to vt.

template <int RELU, int VT>
__global__ __launch_bounds__(256, 4) void gemm_bt(
    const bf16* __restrict__ A, const bf16* __restrict__ Bt,
    const float* __restrict__ bias, bf16* __restrict__ C,
    bf16* __restrict__ vt, int M, int N, int K) {
  __shared__ bf16 As[2][128 * 32];
  __shared__ bf16 Bs[2][128 * 32];
  const int t = threadIdx.x;
  const int w = t >> 6, l = t & 63;
  const int m0 = blockIdx.x * 128, n0 = blockIdx.y * 128;
  const int wr = (w >> 1) * 64, wc = (w & 1) * 64;
  const int srow = l >> 2, schunk = l & 3;  // 16 rows/wave-shot, 4 chunks/row
  const int lm = l & 15, lq = l >> 4;

  f32x4 acc[4][4];
#pragma unroll
  for (int i = 0; i < 4; ++i)
#pragma unroll
    for (int j = 0; j < 4; ++j) acc[i][j] = (f32x4){0.f, 0.f, 0.f, 0.f};

  auto stage = [&](int k0, int d) {
#pragma unroll
    for (int p = 0; p < 2; ++p) {
      int rbase = p * 64 + w * 16;
      int row = rbase + srow;
      int gc = schunk ^ (row & 3);
      async16(&As[d][rbase * 32], A + (size_t)(m0 + row) * K + k0 + gc * 8);
      async16(&Bs[d][rbase * 32], Bt + (size_t)(n0 + row) * K + k0 + gc * 8);
    }
  };

  stage(0, 0);
  const int niter = K >> 5;
  for (int it = 0; it < niter; ++it) {
    const int d = it & 1;
    __syncthreads();  // drains stage(d) [vmcnt] + prev frag reads [lgkm]
    short8 af[4], bfr[4];
#pragma unroll
    for (int mi = 0; mi < 4; ++mi) {
      int rowa = wr + mi * 16 + lm;
      af[mi] = *(const short8*)&As[d][rowa * 32 + ((lq ^ (rowa & 3)) << 3)];
      int rowb = wc + mi * 16 + lm;
      bfr[mi] = *(const short8*)&Bs[d][rowb * 32 + ((lq ^ (rowb & 3)) << 3)];
    }
    if (it + 1 < niter) stage((it + 1) << 5, d ^ 1);
#pragma unroll
    for (int mi = 0; mi < 4; ++mi)
#pragma unroll
      for (int ni = 0; ni < 4; ++ni)
        acc[mi][ni] = __builtin_amdgcn_mfma_f32_16x16x32_bf16(
            af[mi], bfr[ni], acc[mi][ni], 0, 0, 0);
  }

#pragma unroll
  for (int mi = 0; mi < 4; ++mi)
#pragma unroll
    for (int ni = 0; ni < 4; ++ni) {
      int col = n0 + wc + ni * 16 + lm;
      int row0 = m0 + wr + mi * 16 + lq * 4;
      float bv = bias[col];
      float v[4];
#pragma unroll
      for (int r = 0; r < 4; ++r) {
        v[r] = acc[mi][ni][r] + bv;
        if (RELU) v[r] = fmaxf(v[r], 0.f);
        C[(size_t)(row0 + r) * N + col] = __float2bfloat16(v[r]);
      }
      if (VT && col >= 2048) {  // also store V transposed: vt[bh*64+dk][s]
        int vcol = col - 2048;
        int bh = (row0 >> 10) * 16 + (vcol >> 6);
        int dk = vcol & 63;
        int s = row0 & 1023;
        bf16 h4[4] = {__float2bfloat16(v[0]), __float2bfloat16(v[1]),
                      __float2bfloat16(v[2]), __float2bfloat16(v[3])};
        *(uint2*)&vt[((size_t)bh * 64 + dk) * 1024 + s] = *(uint2*)h4;
      }
    }
}

// split-K variant: blockIdx.z = split s; writes raw partial to P + s*M*N.
__global__ __launch_bounds__(256, 4) void gemm_bt_splitk(
    const bf16* __restrict__ A, const bf16* __restrict__ Bt,
    bf16* __restrict__ P, int M, int N, int lda, int KS) {
  __shared__ bf16 As[2][128 * 32];
  __shared__ bf16 Bs[2][128 * 32];
  const int t = threadIdx.x;
  const int w = t >> 6, l = t & 63;
  const int m0 = blockIdx.x * 128, n0 = blockIdx.y * 128;
  const int kstart = blockIdx.z * KS;
  const int wr = (w >> 1) * 64, wc = (w & 1) * 64;
  const int srow = l >> 2, schunk = l & 3;
  const int lm = l & 15, lq = l >> 4;

  f32x4 acc[4][4];
#pragma unroll
  for (int i = 0; i < 4; ++i)
#pragma unroll
    for (int j = 0; j < 4; ++j) acc[i][j] = (f32x4){0.f, 0.f, 0.f, 0.f};

  auto stage = [&](int k0, int d) {
#pragma unroll
    for (int p = 0; p < 2; ++p) {
      int rbase = p * 64 + w * 16;
      int row = rbase + srow;
      int gc = schunk ^ (row & 3);
      async16(&As[d][rbase * 32], A + (size_t)(m0 + row) * lda + k0 + gc * 8);
      async16(&Bs[d][rbase * 32], Bt + (size_t)(n0 + row) * lda + k0 + gc * 8);
    }
  };

  stage(kstart, 0);
  const int niter = KS >> 5;
  for (int it = 0; it < niter; ++it) {
    const int d = it & 1;
    __syncthreads();
    short8 af[4], bfr[4];
#pragma unroll
    for (int mi = 0; mi < 4; ++mi) {
      int rowa = wr + mi * 16 + lm;
      af[mi] = *(const short8*)&As[d][rowa * 32 + ((lq ^ (rowa & 3)) << 3)];
      int rowb = wc + mi * 16 + lm;
      bfr[mi] = *(const short8*)&Bs[d][rowb * 32 + ((lq ^ (rowb & 3)) << 3)];
    }
    if (it + 1 < niter) stage(kstart + ((it + 1) << 5), d ^ 1);
#pragma unroll
    for (int mi = 0; mi < 4; ++mi)
#pragma unroll
      for (int ni = 0; ni < 4; ++ni)
        acc[mi][ni] = __builtin_amdgcn_mfma_f32_16x16x32_bf16(
            af[mi], bfr[ni], acc[mi][ni], 0, 0, 0);
  }
  bf16* Pz = P + (size_t)blockIdx.z * M * N;
#pragma unroll
  for (int mi = 0; mi < 4; ++mi)
#pragma unroll
    for (int r = 0; r < 4; ++r) {
      int row = m0 + wr + mi * 16 + lq * 4 + r;
#pragma unroll
      for (int ni = 0; ni < 4; ++ni) {
        int col = n0 + wc + ni * 16 + lm;
        Pz[(size_t)row * N + col] = __float2bfloat16(acc[mi][ni][r]);
      }
    }
}

// ---------------- flash attention (bounded-score softmax) ----------------

__global__ __launch_bounds__(512, 4) void flash_attn(
    const bf16* __restrict__ qkv, const bf16* __restrict__ vt,
    const float* __restrict__ rel, const int* __restrict__ mask,
    bf16* __restrict__ ctx) {
  __shared__ bf16 Kl[2][64 * 64];
  __shared__ bf16 Vl[2][64 * 64];
  __shared__ bf16 Pl[128 * 64];
  __shared__ float bias_s[2][192];
  __shared__ float mask_s[2][64];

  const int t = threadIdx.x;
  const int w = t >> 6, l = t & 63;
  const int lm = l & 15, lq = l >> 4;
  const int qt = blockIdx.x, bh = blockIdx.y;
  const int b = bh >> 4, h = bh & 15;
  const int q0 = qt * 128;
  const int srow = l >> 3;
  const int gc = (l & 7) ^ srow;
  const int qq = w * 16 + lm;

  auto stage = [&](int d, int k0n) {
    async16(&Kl[d][w * 8 * 64],
            qkv + (size_t)(b * 1024 + k0n + w * 8 + srow) * 3072 + 1024 + h * 64 + gc * 8);
    async16(&Vl[d][w * 8 * 64],
            vt + ((size_t)bh * 64 + w * 8 + srow) * 1024 + k0n + gc * 8);
    if (t < 191) bias_s[d][t] = rel[(q0 - k0n + 960 + t) * 16 + h] * LOG2E;
    if (t < 64) mask_s[d][t] = (mask[b * 1024 + k0n + t] == 0) ? -1.44e9f : 0.f;
  };

#pragma unroll
  for (int p = 0; p < 2; ++p)
    async16(&Pl[(p * 64 + w * 8) * 64],
            qkv + (size_t)(b * 1024 + q0 + p * 64 + w * 8 + srow) * 3072 + h * 64 + gc * 8);
  stage(0, 0);
  __syncthreads();

  short8 qf[2];
#pragma unroll
  for (int kk = 0; kk < 2; ++kk)
    qf[kk] = *(const short8*)&Pl[qq * 64 + (((kk * 4 + lq) ^ (lm & 7)) << 3)];
  __syncthreads();

  float l_acc = 0.f;
  f32x4 acc_o[4];
#pragma unroll
  for (int j = 0; j < 4; ++j) acc_o[j] = (f32x4){0.f, 0.f, 0.f, 0.f};

  const float C0 = 0.125f * LOG2E;

  for (int kt = 0; kt < 16; ++kt) {
    const int d = kt & 1;
    if (kt < 15) stage(d ^ 1, (kt + 1) * 64);

    f32x4 sa[4];
#pragma unroll
    for (int i = 0; i < 4; ++i) sa[i] = (f32x4){0.f, 0.f, 0.f, 0.f};
#pragma unroll
    for (int kk = 0; kk < 2; ++kk) {
      short8 ak[4];
#pragma unroll
      for (int mi = 0; mi < 4; ++mi) {
        int row = mi * 16 + lm;
        ak[mi] = *(const short8*)&Kl[d][row * 64 + (((kk * 4 + lq) ^ (lm & 7)) << 3)];
      }
#pragma unroll
      for (int mi = 0; mi < 4; ++mi)
        sa[mi] = __builtin_amdgcn_mfma_f32_16x16x32_bf16(ak[mi], qf[kk], sa[mi], 0, 0, 0);
    }

    float m4[4][4];
#pragma unroll
    for (int mi = 0; mi < 4; ++mi)
      *(float4*)m4[mi] = *(const float4*)&mask_s[d][mi * 16 + lq * 4];
#pragma unroll
    for (int mi = 0; mi < 4; ++mi)
#pragma unroll
      for (int r = 0; r < 4; ++r) {
        int kl = mi * 16 + lq * 4 + r;
        float p = __builtin_amdgcn_exp2f(
            fmaf(sa[mi][r], C0, bias_s[d][qq - kl + 63] + m4[mi][r]));
        sa[mi][r] = p;
        l_acc += p;
      }

#pragma unroll
    for (int mi = 0; mi < 4; ++mi) {
      bf16 h4[4];
#pragma unroll
      for (int r = 0; r < 4; ++r) h4[r] = __float2bfloat16(sa[mi][r]);
      int chunk = mi * 2 + (lq >> 1);
      *(uint2*)&Pl[qq * 64 + ((chunk ^ (lm & 7)) << 3) + ((lq & 1) << 2)] =
          *(uint2*)h4;
    }

#pragma unroll
    for (int kk2 = 0; kk2 < 2; ++kk2) {
      short8 pf = *(const short8*)&Pl[qq * 64 + (((kk2 * 4 + lq) ^ (lm & 7)) << 3)];
      short8 vf[4];
#pragma unroll
      for (int ni = 0; ni < 4; ++ni) {
        int rowv = ni * 16 + lm;
        vf[ni] = *(const short8*)&Vl[d][rowv * 64 + (((kk2 * 4 + lq) ^ (lm & 7)) << 3)];
      }
#pragma unroll
      for (int ni = 0; ni < 4; ++ni)
        acc_o[ni] = __builtin_amdgcn_mfma_f32_16x16x32_bf16(pf, vf[ni], acc_o[ni], 0, 0, 0);
    }
    __syncthreads();
  }

  l_acc += __shfl_xor(l_acc, 16);
  l_acc += __shfl_xor(l_acc, 32);
  float linv = 1.f / l_acc;
#pragma unroll
  for (int r = 0; r < 4; ++r) {
    float il = __shfl(linv, lq * 4 + r);
    int qx = w * 16 + lq * 4 + r;
    size_t rowbase = (size_t)(b * 1024 + q0 + qx) * 1024 + h * 64;
#pragma unroll
    for (int ni = 0; ni < 4; ++ni)
      ctx[rowbase + ni * 16 + lm] = __float2bfloat16(acc_o[ni][r] * il);
  }
}

// ---------------- residual + split-K reduce + bias + layernorm ----------------

template <int NS>
__global__ __launch_bounds__(256) void ln_resid(
    const float* __restrict__ xin, const bf16* __restrict__ part,
    const float* __restrict__ bias,
    const float* __restrict__ gw, const float* __restrict__ bw,
    float* __restrict__ outf, bf16* __restrict__ outb) {
  const int row = blockIdx.x, t = threadIdx.x;
  const size_t base = (size_t)row * 1024 + t * 4;
  float4 xv = *(const float4*)(xin + base);
  float4 bi = *(const float4*)(bias + t * 4);
  float v0 = xv.x + bi.x, v1 = xv.y + bi.y, v2 = xv.z + bi.z, v3 = xv.w + bi.w;
#pragma unroll
  for (int s = 0; s < NS; ++s) {
    const bf16* p = part + (size_t)s * 4194304 + base;
    ushort4 pv = *(const ushort4*)p;
    v0 += bf2f(pv.x); v1 += bf2f(pv.y); v2 += bf2f(pv.z); v3 += bf2f(pv.w);
  }
  float s1 = v0 + v1 + v2 + v3;
  float s2 = v0 * v0 + v1 * v1 + v2 * v2 + v3 * v3;
#pragma unroll
  for (int o = 1; o < 64; o <<= 1) {
    s1 += __shfl_xor(s1, o);
    s2 += __shfl_xor(s2, o);
  }
  __shared__ float red[8];
  const int w = t >> 6, l = t & 63;
  if (l == 0) { red[w] = s1; red[4 + w] = s2; }
  __syncthreads();
  float S1 = red[0] + red[1] + red[2] + red[3];
  float S2 = red[4] + red[5] + red[6] + red[7];
  float mean = S1 * (1.f / 1024.f);
  float var = S2 * (1.f / 1024.f) - mean * mean;
  float rstd = rsqrtf(var + 1e-5f);
  float4 gv = *(const float4*)(gw + t * 4);
  float4 bv = *(const float4*)(bw + t * 4);
  float o0 = (v0 - mean) * rstd * gv.x + bv.x;
  float o1 = (v1 - mean) * rstd * gv.y + bv.y;
  float o2 = (v2 - mean) * rstd * gv.z + bv.z;
  float o3 = (v3 - mean) * rstd * gv.w + bv.w;
  if (outf) {
    float4 ov = {o0, o1, o2, o3};
    *(float4*)(outf + base) = ov;
  }
  if (outb) {
    bf16 h4[4] = {__float2bfloat16(o0), __float2bfloat16(o1),
                  __float2bfloat16(o2), __float2bfloat16(o3)};
    *(uint2*)((unsigned short*)outb + base) = *(uint2*)h4;
  }
}

// ---------------- launcher ----------------

extern "C" void kernel_launch(void* const* d_in, const int* in_sizes, int n_in,
                              void* d_out, int out_size, void* d_ws, size_t ws_size,
                              hipStream_t stream) {
  (void)in_sizes; (void)n_in; (void)out_size; (void)ws_size;
  const float* x   = (const float*)d_in[0];
  const float* wq  = (const float*)d_in[1];
  const float* bq  = (const float*)d_in[2];
  const float* wk  = (const float*)d_in[3];
  const float* bk  = (const float*)d_in[4];
  const float* wv  = (const float*)d_in[5];
  const float* bv  = (const float*)d_in[6];
  const float* wo  = (const float*)d_in[7];
  const float* bo  = (const float*)d_in[8];
  const float* rel = (const float*)d_in[9];
  const float* g1  = (const float*)d_in[10];
  const float* be1 = (const float*)d_in[11];
  const float* w1  = (const float*)d_in[12];
  const float* b1  = (const float*)d_in[13];
  const float* w2  = (const float*)d_in[14];
  const float* b2  = (const float*)d_in[15];
  const float* g2  = (const float*)d_in[16];
  const float* be2 = (const float*)d_in[17];
  const int* mask  = (const int*)d_in[18];
  float* out = (float*)d_out;

  char* ws = (char*)d_ws;
  bf16*  xb      = (bf16*)(ws + 0);
  bf16*  wqkv_t  = (bf16*)(ws + 8388608);
  bf16*  wo_t    = (bf16*)(ws + 14680064);
  bf16*  w1_t    = (bf16*)(ws + 16777216);
  bf16*  ctx_b   = (bf16*)(ws + 25165824);
  bf16*  x1b     = (bf16*)(ws + 33554432);
  bf16*  qkv_b   = (bf16*)(ws + 41943040);
  bf16*  vtb     = (bf16*)(ws + 67108864);
  bf16*  part_wo = (bf16*)(ws + 41943040);   // aliases qkv_b+vtb (dead after flash)
  bf16*  h1      = (bf16*)(ws + 41943040);   // aliases qkv_b+vtb
  bf16*  part_ff = (bf16*)(ws + 0);          // aliases xb..ctx_b (all dead by FFN2)
  bf16*  w2_t    = (bf16*)(ws + 75497472);
  float* x1f     = (float*)(ws + 83886080);
  float* bqkv    = (float*)(ws + 100663296);

  prep_all<<<16385, 256, 0, stream>>>(x, bq, bk, bv, wq, wk, wv, wo, w1, w2,
                                      xb, bqkv, wqkv_t, wo_t, w1_t, w2_t);

  // QKV (+ fused V-transpose into vtb)
  gemm_bt<0, 1><<<dim3(32, 24), 256, 0, stream>>>(
      xb, wqkv_t, bqkv, qkv_b, vtb, 4096, 3072, 1024);
  flash_attn<<<dim3(8, 64), 512, 0, stream>>>(qkv_b, vtb, rel, mask, ctx_b);
  // WO: split-K=4 (1024 blocks, 4/CU)
  gemm_bt_splitk<<<dim3(32, 8, 4), 256, 0, stream>>>(
      ctx_b, wo_t, part_wo, 4096, 1024, 1024, 256);
  ln_resid<4><<<4096, 256, 0, stream>>>(x, part_wo, bo, g1, be1, x1f, x1b);
  gemm_bt<1, 0><<<dim3(32, 32), 256, 0, stream>>>(
      x1b, w1_t, b1, h1, nullptr, 4096, 4096, 1024);
  // FFN2: split-K=4 (1024 blocks, 4/CU)
  gemm_bt_splitk<<<dim3(32, 8, 4), 256, 0, stream>>>(
      h1, w2_t, part_ff, 4096, 1024, 4096, 1024);
  ln_resid<4><<<4096, 256, 0, stream>>>(x1f, part_ff, b2, g2, be2, out, nullptr);
}

// Round 9
// 326.864 us; speedup vs baseline: 1.0278x; 1.0278x over previous
//
#include <hip/hip_runtime.h>
#include <hip/hip_bf16.h>

typedef __hip_bfloat16 bf16;
typedef __attribute__((ext_vector_type(8))) short short8;
typedef __attribute__((ext_vector_type(4))) float f32x4;

#define LOG2E 1.4426950408889634f

typedef const __attribute__((address_space(1))) void* gptr_t;
typedef __attribute__((address_space(3))) void* sptr_t;

__device__ __forceinline__ void async16(void* lds, const void* g) {
  __builtin_amdgcn_global_load_lds((gptr_t)g, (sptr_t)lds, 16, 0, 0);
}

__device__ __forceinline__ float bf2f(unsigned short u) {
  union { unsigned int i; float f; } c; c.i = ((unsigned int)u) << 16; return c.f;
}

// ---------------- merged prep: cast x + concat bias + 6 transposes ----------------

__global__ __launch_bounds__(256) void prep_all(
    const float* __restrict__ x, const float* __restrict__ bq,
    const float* __restrict__ bk, const float* __restrict__ bv,
    const float* __restrict__ wq, const float* __restrict__ wk,
    const float* __restrict__ wv, const float* __restrict__ wo,
    const float* __restrict__ w1, const float* __restrict__ w2,
    bf16* __restrict__ xb, float* __restrict__ bqkv,
    bf16* __restrict__ dqkv, bf16* __restrict__ dwo,
    bf16* __restrict__ dw1, bf16* __restrict__ dw2) {
  const int bid = blockIdx.x;
  if (bid < 4096) {
    int i = (bid * 256 + threadIdx.x) * 4;
    float4 v = *(const float4*)(x + i);
    bf16 h4[4] = {__float2bfloat16(v.x), __float2bfloat16(v.y),
                  __float2bfloat16(v.z), __float2bfloat16(v.w)};
    *(uint2*)((unsigned short*)xb + i) = *(uint2*)h4;
    return;
  }
  if (bid == 16384) {
#pragma unroll
    for (int j = 0; j < 12; ++j) {
      int i = j * 256 + threadIdx.x;
      bqkv[i] = (i < 1024) ? bq[i] : (i < 2048 ? bk[i - 1024] : bv[i - 2048]);
    }
    return;
  }
  __shared__ float tl[32][33];
  const int tid = bid - 4096;
  const float* s;
  bf16* d;
  int NN, KK, n0, k0;
  if (tid < 4096) {
    int m = tid >> 10, tile = tid & 1023;
    s = m == 0 ? wq : m == 1 ? wk : m == 2 ? wv : wo;
    d = m < 3 ? dqkv + (size_t)m * 1024 * 1024 : dwo;
    NN = 1024; KK = 1024;
    n0 = (tile & 31) * 32; k0 = (tile >> 5) * 32;
  } else if (tid < 8192) {
    int tile = tid - 4096;
    s = w1; d = dw1; NN = 4096; KK = 1024;
    n0 = (tile & 127) * 32; k0 = (tile >> 7) * 32;
  } else {
    int tile = tid - 8192;
    s = w2; d = dw2; NN = 1024; KK = 4096;
    n0 = (tile & 31) * 32; k0 = (tile >> 5) * 32;
  }
  const int tx = threadIdx.x & 31, ty = threadIdx.x >> 5;
#pragma unroll
  for (int j = 0; j < 4; ++j)
    tl[ty + j * 8][tx] = s[(size_t)(k0 + ty + j * 8) * NN + n0 + tx];
  __syncthreads();
#pragma unroll
  for (int j = 0; j < 4; ++j)
    d[(size_t)(n0 + ty + j * 8) * KK + k0 + tx] =
        __float2bfloat16(tl[tx][ty + j * 8]);
}

// ---------------- GEMM: C[M][N] = A[M][K] * Bt[N][K]^T + bias ----------------
// BK=32 double-buffer (32 KB LDS), ONE barrier per K-tile, 4 blocks/CU.
// Swizzle: LDS slot s of row r holds global chunk s ^ ((r>>1)&3).
// Bank index = (r&1)*16 + slot*4 + w; (r&1, (r>>1)&3) is a bijection mod 8 rows
// => every 16-lane read phase hits each 4-bank group exactly 2x (free).
// blockIdx.x = M-tile => XCD-local A-slab reuse in L2.

template <int RELU, int VT>
__global__ __launch_bounds__(256, 4) void gemm_bt(
    const bf16* __restrict__ A, const bf16* __restrict__ Bt,
    const float* __restrict__ bias, bf16* __restrict__ C,
    bf16* __restrict__ vt, int M, int N, int K) {
  __shared__ bf16 As[2][128 * 32];
  __shared__ bf16 Bs[2][128 * 32];
  const int t = threadIdx.x;
  const int w = t >> 6, l = t & 63;
  const int m0 = blockIdx.x * 128, n0 = blockIdx.y * 128;
  const int wr = (w >> 1) * 64, wc = (w & 1) * 64;
  const int srow = l >> 2, schunk = l & 3;
  const int lm = l & 15, lq = l >> 4;

  f32x4 acc[4][4];
#pragma unroll
  for (int i = 0; i < 4; ++i)
#pragma unroll
    for (int j = 0; j < 4; ++j) acc[i][j] = (f32x4){0.f, 0.f, 0.f, 0.f};

  auto stage = [&](int k0, int d) {
#pragma unroll
    for (int p = 0; p < 2; ++p) {
      int rbase = p * 64 + w * 16;
      int row = rbase + srow;
      int gc = schunk ^ ((row >> 1) & 3);
      async16(&As[d][rbase * 32], A + (size_t)(m0 + row) * K + k0 + gc * 8);
      async16(&Bs[d][rbase * 32], Bt + (size_t)(n0 + row) * K + k0 + gc * 8);
    }
  };

  stage(0, 0);
  const int niter = K >> 5;
  for (int it = 0; it < niter; ++it) {
    const int d = it & 1;
    __syncthreads();  // drains stage(d) [vmcnt] + prev frag reads [lgkm]
    short8 af[4], bfr[4];
#pragma unroll
    for (int mi = 0; mi < 4; ++mi) {
      int rowa = wr + mi * 16 + lm;
      af[mi] = *(const short8*)&As[d][rowa * 32 + ((lq ^ ((rowa >> 1) & 3)) << 3)];
      int rowb = wc + mi * 16 + lm;
      bfr[mi] = *(const short8*)&Bs[d][rowb * 32 + ((lq ^ ((rowb >> 1) & 3)) << 3)];
    }
    if (it + 1 < niter) stage((it + 1) << 5, d ^ 1);
#pragma unroll
    for (int mi = 0; mi < 4; ++mi)
#pragma unroll
      for (int ni = 0; ni < 4; ++ni)
        acc[mi][ni] = __builtin_amdgcn_mfma_f32_16x16x32_bf16(
            af[mi], bfr[ni], acc[mi][ni], 0, 0, 0);
  }

#pragma unroll
  for (int mi = 0; mi < 4; ++mi)
#pragma unroll
    for (int ni = 0; ni < 4; ++ni) {
      int col = n0 + wc + ni * 16 + lm;
      int row0 = m0 + wr + mi * 16 + lq * 4;
      float bv = bias[col];
      float v[4];
#pragma unroll
      for (int r = 0; r < 4; ++r) {
        v[r] = acc[mi][ni][r] + bv;
        if (RELU) v[r] = fmaxf(v[r], 0.f);
        C[(size_t)(row0 + r) * N + col] = __float2bfloat16(v[r]);
      }
      if (VT && col >= 2048) {  // also store V transposed: vt[bh*64+dk][s]
        int vcol = col - 2048;
        int bh = (row0 >> 10) * 16 + (vcol >> 6);
        int dk = vcol & 63;
        int s = row0 & 1023;
        bf16 h4[4] = {__float2bfloat16(v[0]), __float2bfloat16(v[1]),
                      __float2bfloat16(v[2]), __float2bfloat16(v[3])};
        *(uint2*)&vt[((size_t)bh * 64 + dk) * 1024 + s] = *(uint2*)h4;
      }
    }
}

// split-K variant: blockIdx.z = split s; writes raw partial to P + s*M*N.
__global__ __launch_bounds__(256, 4) void gemm_bt_splitk(
    const bf16* __restrict__ A, const bf16* __restrict__ Bt,
    bf16* __restrict__ P, int M, int N, int lda, int KS) {
  __shared__ bf16 As[2][128 * 32];
  __shared__ bf16 Bs[2][128 * 32];
  const int t = threadIdx.x;
  const int w = t >> 6, l = t & 63;
  const int m0 = blockIdx.x * 128, n0 = blockIdx.y * 128;
  const int kstart = blockIdx.z * KS;
  const int wr = (w >> 1) * 64, wc = (w & 1) * 64;
  const int srow = l >> 2, schunk = l & 3;
  const int lm = l & 15, lq = l >> 4;

  f32x4 acc[4][4];
#pragma unroll
  for (int i = 0; i < 4; ++i)
#pragma unroll
    for (int j = 0; j < 4; ++j) acc[i][j] = (f32x4){0.f, 0.f, 0.f, 0.f};

  auto stage = [&](int k0, int d) {
#pragma unroll
    for (int p = 0; p < 2; ++p) {
      int rbase = p * 64 + w * 16;
      int row = rbase + srow;
      int gc = schunk ^ ((row >> 1) & 3);
      async16(&As[d][rbase * 32], A + (size_t)(m0 + row) * lda + k0 + gc * 8);
      async16(&Bs[d][rbase * 32], Bt + (size_t)(n0 + row) * lda + k0 + gc * 8);
    }
  };

  stage(kstart, 0);
  const int niter = KS >> 5;
  for (int it = 0; it < niter; ++it) {
    const int d = it & 1;
    __syncthreads();
    short8 af[4], bfr[4];
#pragma unroll
    for (int mi = 0; mi < 4; ++mi) {
      int rowa = wr + mi * 16 + lm;
      af[mi] = *(const short8*)&As[d][rowa * 32 + ((lq ^ ((rowa >> 1) & 3)) << 3)];
      int rowb = wc + mi * 16 + lm;
      bfr[mi] = *(const short8*)&Bs[d][rowb * 32 + ((lq ^ ((rowb >> 1) & 3)) << 3)];
    }
    if (it + 1 < niter) stage(kstart + ((it + 1) << 5), d ^ 1);
#pragma unroll
    for (int mi = 0; mi < 4; ++mi)
#pragma unroll
      for (int ni = 0; ni < 4; ++ni)
        acc[mi][ni] = __builtin_amdgcn_mfma_f32_16x16x32_bf16(
            af[mi], bfr[ni], acc[mi][ni], 0, 0, 0);
  }
  bf16* Pz = P + (size_t)blockIdx.z * M * N;
#pragma unroll
  for (int mi = 0; mi < 4; ++mi)
#pragma unroll
    for (int r = 0; r < 4; ++r) {
      int row = m0 + wr + mi * 16 + lq * 4 + r;
#pragma unroll
      for (int ni = 0; ni < 4; ++ni) {
        int col = n0 + wc + ni * 16 + lm;
        Pz[(size_t)row * N + col] = __float2bfloat16(acc[mi][ni][r]);
      }
    }
}

// ---------------- flash attention (bounded-score softmax) ----------------

__global__ __launch_bounds__(512, 4) void flash_attn(
    const bf16* __restrict__ qkv, const bf16* __restrict__ vt,
    const float* __restrict__ rel, const int* __restrict__ mask,
    bf16* __restrict__ ctx) {
  __shared__ bf16 Kl[2][64 * 64];
  __shared__ bf16 Vl[2][64 * 64];
  __shared__ bf16 Pl[128 * 64];
  __shared__ float bias_s[2][192];
  __shared__ float mask_s[2][64];

  const int t = threadIdx.x;
  const int w = t >> 6, l = t & 63;
  const int lm = l & 15, lq = l >> 4;
  const int qt = blockIdx.x, bh = blockIdx.y;
  const int b = bh >> 4, h = bh & 15;
  const int q0 = qt * 128;
  const int srow = l >> 3;
  const int gc = (l & 7) ^ srow;
  const int qq = w * 16 + lm;

  auto stage = [&](int d, int k0n) {
    async16(&Kl[d][w * 8 * 64],
            qkv + (size_t)(b * 1024 + k0n + w * 8 + srow) * 3072 + 1024 + h * 64 + gc * 8);
    async16(&Vl[d][w * 8 * 64],
            vt + ((size_t)bh * 64 + w * 8 + srow) * 1024 + k0n + gc * 8);
    if (t < 191) bias_s[d][t] = rel[(q0 - k0n + 960 + t) * 16 + h] * LOG2E;
    if (t < 64) mask_s[d][t] = (mask[b * 1024 + k0n + t] == 0) ? -1.44e9f : 0.f;
  };

#pragma unroll
  for (int p = 0; p < 2; ++p)
    async16(&Pl[(p * 64 + w * 8) * 64],
            qkv + (size_t)(b * 1024 + q0 + p * 64 + w * 8 + srow) * 3072 + h * 64 + gc * 8);
  stage(0, 0);
  __syncthreads();

  short8 qf[2];
#pragma unroll
  for (int kk = 0; kk < 2; ++kk)
    qf[kk] = *(const short8*)&Pl[qq * 64 + (((kk * 4 + lq) ^ (lm & 7)) << 3)];
  __syncthreads();

  float l_acc = 0.f;
  f32x4 acc_o[4];
#pragma unroll
  for (int j = 0; j < 4; ++j) acc_o[j] = (f32x4){0.f, 0.f, 0.f, 0.f};

  const float C0 = 0.125f * LOG2E;

  for (int kt = 0; kt < 16; ++kt) {
    const int d = kt & 1;
    if (kt < 15) stage(d ^ 1, (kt + 1) * 64);

    f32x4 sa[4];
#pragma unroll
    for (int i = 0; i < 4; ++i) sa[i] = (f32x4){0.f, 0.f, 0.f, 0.f};
#pragma unroll
    for (int kk = 0; kk < 2; ++kk) {
      short8 ak[4];
#pragma unroll
      for (int mi = 0; mi < 4; ++mi) {
        int row = mi * 16 + lm;
        ak[mi] = *(const short8*)&Kl[d][row * 64 + (((kk * 4 + lq) ^ (lm & 7)) << 3)];
      }
#pragma unroll
      for (int mi = 0; mi < 4; ++mi)
        sa[mi] = __builtin_amdgcn_mfma_f32_16x16x32_bf16(ak[mi], qf[kk], sa[mi], 0, 0, 0);
    }

    float m4[4][4];
#pragma unroll
    for (int mi = 0; mi < 4; ++mi)
      *(float4*)m4[mi] = *(const float4*)&mask_s[d][mi * 16 + lq * 4];
#pragma unroll
    for (int mi = 0; mi < 4; ++mi)
#pragma unroll
      for (int r = 0; r < 4; ++r) {
        int kl = mi * 16 + lq * 4 + r;
        float p = __builtin_amdgcn_exp2f(
            fmaf(sa[mi][r], C0, bias_s[d][qq - kl + 63] + m4[mi][r]));
        sa[mi][r] = p;
        l_acc += p;
      }

#pragma unroll
    for (int mi = 0; mi < 4; ++mi) {
      bf16 h4[4];
#pragma unroll
      for (int r = 0; r < 4; ++r) h4[r] = __float2bfloat16(sa[mi][r]);
      int chunk = mi * 2 + (lq >> 1);
      *(uint2*)&Pl[qq * 64 + ((chunk ^ (lm & 7)) << 3) + ((lq & 1) << 2)] =
          *(uint2*)h4;
    }

#pragma unroll
    for (int kk2 = 0; kk2 < 2; ++kk2) {
      short8 pf = *(const short8*)&Pl[qq * 64 + (((kk2 * 4 + lq) ^ (lm & 7)) << 3)];
      short8 vf[4];
#pragma unroll
      for (int ni = 0; ni < 4; ++ni) {
        int rowv = ni * 16 + lm;
        vf[ni] = *(const short8*)&Vl[d][rowv * 64 + (((kk2 * 4 + lq) ^ (lm & 7)) << 3)];
      }
#pragma unroll
      for (int ni = 0; ni < 4; ++ni)
        acc_o[ni] = __builtin_amdgcn_mfma_f32_16x16x32_bf16(pf, vf[ni], acc_o[ni], 0, 0, 0);
    }
    __syncthreads();
  }

  l_acc += __shfl_xor(l_acc, 16);
  l_acc += __shfl_xor(l_acc, 32);
  float linv = 1.f / l_acc;
#pragma unroll
  for (int r = 0; r < 4; ++r) {
    float il = __shfl(linv, lq * 4 + r);
    int qx = w * 16 + lq * 4 + r;
    size_t rowbase = (size_t)(b * 1024 + q0 + qx) * 1024 + h * 64;
#pragma unroll
    for (int ni = 0; ni < 4; ++ni)
      ctx[rowbase + ni * 16 + lm] = __float2bfloat16(acc_o[ni][r] * il);
  }
}

// ---------------- residual + split-K reduce + bias + layernorm ----------------

template <int NS>
__global__ __launch_bounds__(256) void ln_resid(
    const float* __restrict__ xin, const bf16* __restrict__ part,
    const float* __restrict__ bias,
    const float* __restrict__ gw, const float* __restrict__ bw,
    float* __restrict__ outf, bf16* __restrict__ outb) {
  const int row = blockIdx.x, t = threadIdx.x;
  const size_t base = (size_t)row * 1024 + t * 4;
  float4 xv = *(const float4*)(xin + base);
  float4 bi = *(const float4*)(bias + t * 4);
  float v0 = xv.x + bi.x, v1 = xv.y + bi.y, v2 = xv.z + bi.z, v3 = xv.w + bi.w;
#pragma unroll
  for (int s = 0; s < NS; ++s) {
    const bf16* p = part + (size_t)s * 4194304 + base;
    ushort4 pv = *(const ushort4*)p;
    v0 += bf2f(pv.x); v1 += bf2f(pv.y); v2 += bf2f(pv.z); v3 += bf2f(pv.w);
  }
  float s1 = v0 + v1 + v2 + v3;
  float s2 = v0 * v0 + v1 * v1 + v2 * v2 + v3 * v3;
#pragma unroll
  for (int o = 1; o < 64; o <<= 1) {
    s1 += __shfl_xor(s1, o);
    s2 += __shfl_xor(s2, o);
  }
  __shared__ float red[8];
  const int w = t >> 6, l = t & 63;
  if (l == 0) { red[w] = s1; red[4 + w] = s2; }
  __syncthreads();
  float S1 = red[0] + red[1] + red[2] + red[3];
  float S2 = red[4] + red[5] + red[6] + red[7];
  float mean = S1 * (1.f / 1024.f);
  float var = S2 * (1.f / 1024.f) - mean * mean;
  float rstd = rsqrtf(var + 1e-5f);
  float4 gv = *(const float4*)(gw + t * 4);
  float4 bv = *(const float4*)(bw + t * 4);
  float o0 = (v0 - mean) * rstd * gv.x + bv.x;
  float o1 = (v1 - mean) * rstd * gv.y + bv.y;
  float o2 = (v2 - mean) * rstd * gv.z + bv.z;
  float o3 = (v3 - mean) * rstd * gv.w + bv.w;
  if (outf) {
    float4 ov = {o0, o1, o2, o3};
    *(float4*)(outf + base) = ov;
  }
  if (outb) {
    bf16 h4[4] = {__float2bfloat16(o0), __float2bfloat16(o1),
                  __float2bfloat16(o2), __float2bfloat16(o3)};
    *(uint2*)((unsigned short*)outb + base) = *(uint2*)h4;
  }
}

// ---------------- launcher ----------------

extern "C" void kernel_launch(void* const* d_in, const int* in_sizes, int n_in,
                              void* d_out, int out_size, void* d_ws, size_t ws_size,
                              hipStream_t stream) {
  (void)in_sizes; (void)n_in; (void)out_size; (void)ws_size;
  const float* x   = (const float*)d_in[0];
  const float* wq  = (const float*)d_in[1];
  const float* bq  = (const float*)d_in[2];
  const float* wk  = (const float*)d_in[3];
  const float* bk  = (const float*)d_in[4];
  const float* wv  = (const float*)d_in[5];
  const float* bv  = (const float*)d_in[6];
  const float* wo  = (const float*)d_in[7];
  const float* bo  = (const float*)d_in[8];
  const float* rel = (const float*)d_in[9];
  const float* g1  = (const float*)d_in[10];
  const float* be1 = (const float*)d_in[11];
  const float* w1  = (const float*)d_in[12];
  const float* b1  = (const float*)d_in[13];
  const float* w2  = (const float*)d_in[14];
  const float* b2  = (const float*)d_in[15];
  const float* g2  = (const float*)d_in[16];
  const float* be2 = (const float*)d_in[17];
  const int* mask  = (const int*)d_in[18];
  float* out = (float*)d_out;

  char* ws = (char*)d_ws;
  bf16*  xb      = (bf16*)(ws + 0);
  bf16*  wqkv_t  = (bf16*)(ws + 8388608);
  bf16*  wo_t    = (bf16*)(ws + 14680064);
  bf16*  w1_t    = (bf16*)(ws + 16777216);
  bf16*  ctx_b   = (bf16*)(ws + 25165824);
  bf16*  x1b     = (bf16*)(ws + 33554432);
  bf16*  qkv_b   = (bf16*)(ws + 41943040);
  bf16*  vtb     = (bf16*)(ws + 67108864);
  bf16*  part_wo = (bf16*)(ws + 41943040);   // aliases qkv_b+vtb (dead after flash)
  bf16*  h1      = (bf16*)(ws + 41943040);   // aliases qkv_b+vtb
  bf16*  part_ff = (bf16*)(ws + 0);          // aliases xb..ctx_b (all dead by FFN2)
  bf16*  w2_t    = (bf16*)(ws + 75497472);
  float* x1f     = (float*)(ws + 83886080);
  float* bqkv    = (float*)(ws + 100663296);

  prep_all<<<16385, 256, 0, stream>>>(x, bq, bk, bv, wq, wk, wv, wo, w1, w2,
                                      xb, bqkv, wqkv_t, wo_t, w1_t, w2_t);

  // QKV (+ fused V-transpose into vtb)
  gemm_bt<0, 1><<<dim3(32, 24), 256, 0, stream>>>(
      xb, wqkv_t, bqkv, qkv_b, vtb, 4096, 3072, 1024);
  flash_attn<<<dim3(8, 64), 512, 0, stream>>>(qkv_b, vtb, rel, mask, ctx_b);
  // WO: split-K=4 (1024 blocks, 4/CU)
  gemm_bt_splitk<<<dim3(32, 8, 4), 256, 0, stream>>>(
      ctx_b, wo_t, part_wo, 4096, 1024, 1024, 256);
  ln_resid<4><<<4096, 256, 0, stream>>>(x, part_wo, bo, g1, be1, x1f, x1b);
  gemm_bt<1, 0><<<dim3(32, 32), 256, 0, stream>>>(
      x1b, w1_t, b1, h1, nullptr, 4096, 4096, 1024);
  // FFN2: split-K=4 (1024 blocks, 4/CU)
  gemm_bt_splitk<<<dim3(32, 8, 4), 256, 0, stream>>>(
      h1, w2_t, part_ff, 4096, 1024, 4096, 1024);
  ln_resid<4><<<4096, 256, 0, stream>>>(x1f, part_ff, b2, g2, be2, out, nullptr);
}

// Round 10
// 323.185 us; speedup vs baseline: 1.0395x; 1.0114x over previous
//
#include <hip/hip_runtime.h>
#include <hip/hip_bf16.h>

typedef __hip_bfloat16 bf16;
typedef __attribute__((ext_vector_type(8))) short short8;
typedef __attribute__((ext_vector_type(4))) float f32x4;

#define LOG2E 1.4426950408889634f

typedef const __attribute__((address_space(1))) void* gptr_t;
typedef __attribute__((address_space(3))) void* sptr_t;

__device__ __forceinline__ void async16(void* lds, const void* g) {
  __builtin_amdgcn_global_load_lds((gptr_t)g, (sptr_t)lds, 16, 0, 0);
}

__device__ __forceinline__ float bf2f(unsigned short u) {
  union { unsigned int i; float f; } c; c.i = ((unsigned int)u) << 16; return c.f;
}

// ---------------- merged prep: cast x + concat bias + 6 transposes ----------------

__global__ __launch_bounds__(256) void prep_all(
    const float* __restrict__ x, const float* __restrict__ bq,
    const float* __restrict__ bk, const float* __restrict__ bv,
    const float* __restrict__ wq, const float* __restrict__ wk,
    const float* __restrict__ wv, const float* __restrict__ wo,
    const float* __restrict__ w1, const float* __restrict__ w2,
    bf16* __restrict__ xb, float* __restrict__ bqkv,
    bf16* __restrict__ dqkv, bf16* __restrict__ dwo,
    bf16* __restrict__ dw1, bf16* __restrict__ dw2) {
  const int bid = blockIdx.x;
  if (bid < 4096) {
    int i = (bid * 256 + threadIdx.x) * 4;
    float4 v = *(const float4*)(x + i);
    bf16 h4[4] = {__float2bfloat16(v.x), __float2bfloat16(v.y),
                  __float2bfloat16(v.z), __float2bfloat16(v.w)};
    *(uint2*)((unsigned short*)xb + i) = *(uint2*)h4;
    return;
  }
  if (bid == 16384) {
#pragma unroll
    for (int j = 0; j < 12; ++j) {
      int i = j * 256 + threadIdx.x;
      bqkv[i] = (i < 1024) ? bq[i] : (i < 2048 ? bk[i - 1024] : bv[i - 2048]);
    }
    return;
  }
  __shared__ float tl[32][33];
  const int tid = bid - 4096;
  const float* s;
  bf16* d;
  int NN, KK, n0, k0;
  if (tid < 4096) {
    int m = tid >> 10, tile = tid & 1023;
    s = m == 0 ? wq : m == 1 ? wk : m == 2 ? wv : wo;
    d = m < 3 ? dqkv + (size_t)m * 1024 * 1024 : dwo;
    NN = 1024; KK = 1024;
    n0 = (tile & 31) * 32; k0 = (tile >> 5) * 32;
  } else if (tid < 8192) {
    int tile = tid - 4096;
    s = w1; d = dw1; NN = 4096; KK = 1024;
    n0 = (tile & 127) * 32; k0 = (tile >> 7) * 32;
  } else {
    int tile = tid - 8192;
    s = w2; d = dw2; NN = 1024; KK = 4096;
    n0 = (tile & 31) * 32; k0 = (tile >> 5) * 32;
  }
  const int tx = threadIdx.x & 31, ty = threadIdx.x >> 5;
#pragma unroll
  for (int j = 0; j < 4; ++j)
    tl[ty + j * 8][tx] = s[(size_t)(k0 + ty + j * 8) * NN + n0 + tx];
  __syncthreads();
#pragma unroll
  for (int j = 0; j < 4; ++j)
    d[(size_t)(n0 + ty + j * 8) * KK + k0 + tx] =
        __float2bfloat16(tl[tx][ty + j * 8]);
}

// ---------------- GEMM: C[M][N] = A[M][K] * Bt[N][K]^T + bias ----------------
// BK=64 double-buffer (64 KB LDS), ONE barrier per K-tile (measured best: the
// larger per-iteration compute block covers the vmcnt(0) drain latency that
// BK=32 could not). blockIdx.x = M-tile (32%8==0) => A-slab pinned per XCD.
// Swizzle chunk^(row&7): 128B row stride makes row drop out of bank index;
// measured 0 bank conflicts.

template <int RELU, int VT>
__global__ __launch_bounds__(256) void gemm_bt(
    const bf16* __restrict__ A, const bf16* __restrict__ Bt,
    const float* __restrict__ bias, bf16* __restrict__ C,
    bf16* __restrict__ vt, int M, int N, int K) {
  __shared__ bf16 As[2][128 * 64];
  __shared__ bf16 Bs[2][128 * 64];
  const int t = threadIdx.x;
  const int w = t >> 6, l = t & 63;
  const int m0 = blockIdx.x * 128, n0 = blockIdx.y * 128;
  const int wr = (w >> 1) * 64, wc = (w & 1) * 64;
  const int srow = l >> 3, scol = l & 7;
  const int lm = l & 15, lq = l >> 4;

  f32x4 acc[4][4];
#pragma unroll
  for (int i = 0; i < 4; ++i)
#pragma unroll
    for (int j = 0; j < 4; ++j) acc[i][j] = (f32x4){0.f, 0.f, 0.f, 0.f};

  auto stage = [&](int k0, int d) {
#pragma unroll
    for (int p = 0; p < 4; ++p) {
      int row = p * 32 + w * 8 + srow;
      int gc = scol ^ (row & 7);
      async16(&As[d][(p * 32 + w * 8) * 64], A + (size_t)(m0 + row) * K + k0 + gc * 8);
      async16(&Bs[d][(p * 32 + w * 8) * 64], Bt + (size_t)(n0 + row) * K + k0 + gc * 8);
    }
  };

  stage(0, 0);
  const int niter = K >> 6;
  for (int it = 0; it < niter; ++it) {
    const int d = it & 1;
    __syncthreads();  // drains stage(d) [vmcnt] + prev frag reads [lgkm]
    short8 af[2][4], bfr[2][4];
#pragma unroll
    for (int kk = 0; kk < 2; ++kk)
#pragma unroll
      for (int mi = 0; mi < 4; ++mi) {
        int rowa = wr + mi * 16 + lm;
        af[kk][mi] = *(const short8*)&As[d][rowa * 64 + (((kk * 4 + lq) ^ (rowa & 7)) << 3)];
        int rowb = wc + mi * 16 + lm;
        bfr[kk][mi] = *(const short8*)&Bs[d][rowb * 64 + (((kk * 4 + lq) ^ (rowb & 7)) << 3)];
      }
    if (it + 1 < niter) stage((it + 1) << 6, d ^ 1);
#pragma unroll
    for (int kk = 0; kk < 2; ++kk)
#pragma unroll
      for (int mi = 0; mi < 4; ++mi)
#pragma unroll
        for (int ni = 0; ni < 4; ++ni)
          acc[mi][ni] = __builtin_amdgcn_mfma_f32_16x16x32_bf16(
              af[kk][mi], bfr[kk][ni], acc[mi][ni], 0, 0, 0);
  }

#pragma unroll
  for (int mi = 0; mi < 4; ++mi)
#pragma unroll
    for (int ni = 0; ni < 4; ++ni) {
      int col = n0 + wc + ni * 16 + lm;
      int row0 = m0 + wr + mi * 16 + lq * 4;
      float bv = bias[col];
      float v[4];
#pragma unroll
      for (int r = 0; r < 4; ++r) {
        v[r] = acc[mi][ni][r] + bv;
        if (RELU) v[r] = fmaxf(v[r], 0.f);
        C[(size_t)(row0 + r) * N + col] = __float2bfloat16(v[r]);
      }
      if (VT && col >= 2048) {  // also store V transposed: vt[bh*64+dk][s]
        int vcol = col - 2048;
        int bh = (row0 >> 10) * 16 + (vcol >> 6);
        int dk = vcol & 63;
        int s = row0 & 1023;
        bf16 h4[4] = {__float2bfloat16(v[0]), __float2bfloat16(v[1]),
                      __float2bfloat16(v[2]), __float2bfloat16(v[3])};
        *(uint2*)&vt[((size_t)bh * 64 + dk) * 1024 + s] = *(uint2*)h4;
      }
    }
}

// split-K variant: blockIdx.z = split s; writes raw partial to P + s*M*N.
__global__ __launch_bounds__(256) void gemm_bt_splitk(
    const bf16* __restrict__ A, const bf16* __restrict__ Bt,
    bf16* __restrict__ P, int M, int N, int lda, int KS) {
  __shared__ bf16 As[2][128 * 64];
  __shared__ bf16 Bs[2][128 * 64];
  const int t = threadIdx.x;
  const int w = t >> 6, l = t & 63;
  const int m0 = blockIdx.x * 128, n0 = blockIdx.y * 128;
  const int kstart = blockIdx.z * KS;
  const int wr = (w >> 1) * 64, wc = (w & 1) * 64;
  const int srow = l >> 3, scol = l & 7;
  const int lm = l & 15, lq = l >> 4;

  f32x4 acc[4][4];
#pragma unroll
  for (int i = 0; i < 4; ++i)
#pragma unroll
    for (int j = 0; j < 4; ++j) acc[i][j] = (f32x4){0.f, 0.f, 0.f, 0.f};

  auto stage = [&](int k0, int d) {
#pragma unroll
    for (int p = 0; p < 4; ++p) {
      int row = p * 32 + w * 8 + srow;
      int gc = scol ^ (row & 7);
      async16(&As[d][(p * 32 + w * 8) * 64], A + (size_t)(m0 + row) * lda + k0 + gc * 8);
      async16(&Bs[d][(p * 32 + w * 8) * 64], Bt + (size_t)(n0 + row) * lda + k0 + gc * 8);
    }
  };

  stage(kstart, 0);
  const int niter = KS >> 6;
  for (int it = 0; it < niter; ++it) {
    const int d = it & 1;
    __syncthreads();
    short8 af[2][4], bfr[2][4];
#pragma unroll
    for (int kk = 0; kk < 2; ++kk)
#pragma unroll
      for (int mi = 0; mi < 4; ++mi) {
        int rowa = wr + mi * 16 + lm;
        af[kk][mi] = *(const short8*)&As[d][rowa * 64 + (((kk * 4 + lq) ^ (rowa & 7)) << 3)];
        int rowb = wc + mi * 16 + lm;
        bfr[kk][mi] = *(const short8*)&Bs[d][rowb * 64 + (((kk * 4 + lq) ^ (rowb & 7)) << 3)];
      }
    if (it + 1 < niter) stage(kstart + ((it + 1) << 6), d ^ 1);
#pragma unroll
    for (int kk = 0; kk < 2; ++kk)
#pragma unroll
      for (int mi = 0; mi < 4; ++mi)
#pragma unroll
        for (int ni = 0; ni < 4; ++ni)
          acc[mi][ni] = __builtin_amdgcn_mfma_f32_16x16x32_bf16(
              af[kk][mi], bfr[kk][ni], acc[mi][ni], 0, 0, 0);
  }
  bf16* Pz = P + (size_t)blockIdx.z * M * N;
#pragma unroll
  for (int mi = 0; mi < 4; ++mi)
#pragma unroll
    for (int r = 0; r < 4; ++r) {
      int row = m0 + wr + mi * 16 + lq * 4 + r;
#pragma unroll
      for (int ni = 0; ni < 4; ++ni) {
        int col = n0 + wc + ni * 16 + lm;
        Pz[(size_t)row * N + col] = __float2bfloat16(acc[mi][ni][r]);
      }
    }
}

// ---------------- flash attention (bounded-score softmax) ----------------

__global__ __launch_bounds__(512, 4) void flash_attn(
    const bf16* __restrict__ qkv, const bf16* __restrict__ vt,
    const float* __restrict__ rel, const int* __restrict__ mask,
    bf16* __restrict__ ctx) {
  __shared__ bf16 Kl[2][64 * 64];
  __shared__ bf16 Vl[2][64 * 64];
  __shared__ bf16 Pl[128 * 64];
  __shared__ float bias_s[2][192];
  __shared__ float mask_s[2][64];

  const int t = threadIdx.x;
  const int w = t >> 6, l = t & 63;
  const int lm = l & 15, lq = l >> 4;
  const int qt = blockIdx.x, bh = blockIdx.y;
  const int b = bh >> 4, h = bh & 15;
  const int q0 = qt * 128;
  const int srow = l >> 3;
  const int gc = (l & 7) ^ srow;
  const int qq = w * 16 + lm;

  auto stage = [&](int d, int k0n) {
    async16(&Kl[d][w * 8 * 64],
            qkv + (size_t)(b * 1024 + k0n + w * 8 + srow) * 3072 + 1024 + h * 64 + gc * 8);
    async16(&Vl[d][w * 8 * 64],
            vt + ((size_t)bh * 64 + w * 8 + srow) * 1024 + k0n + gc * 8);
    if (t < 191) bias_s[d][t] = rel[(q0 - k0n + 960 + t) * 16 + h] * LOG2E;
    if (t < 64) mask_s[d][t] = (mask[b * 1024 + k0n + t] == 0) ? -1.44e9f : 0.f;
  };

#pragma unroll
  for (int p = 0; p < 2; ++p)
    async16(&Pl[(p * 64 + w * 8) * 64],
            qkv + (size_t)(b * 1024 + q0 + p * 64 + w * 8 + srow) * 3072 + h * 64 + gc * 8);
  stage(0, 0);
  __syncthreads();

  short8 qf[2];
#pragma unroll
  for (int kk = 0; kk < 2; ++kk)
    qf[kk] = *(const short8*)&Pl[qq * 64 + (((kk * 4 + lq) ^ (lm & 7)) << 3)];
  __syncthreads();

  float l_acc = 0.f;
  f32x4 acc_o[4];
#pragma unroll
  for (int j = 0; j < 4; ++j) acc_o[j] = (f32x4){0.f, 0.f, 0.f, 0.f};

  const float C0 = 0.125f * LOG2E;

  for (int kt = 0; kt < 16; ++kt) {
    const int d = kt & 1;
    if (kt < 15) stage(d ^ 1, (kt + 1) * 64);

    f32x4 sa[4];
#pragma unroll
    for (int i = 0; i < 4; ++i) sa[i] = (f32x4){0.f, 0.f, 0.f, 0.f};
#pragma unroll
    for (int kk = 0; kk < 2; ++kk) {
      short8 ak[4];
#pragma unroll
      for (int mi = 0; mi < 4; ++mi) {
        int row = mi * 16 + lm;
        ak[mi] = *(const short8*)&Kl[d][row * 64 + (((kk * 4 + lq) ^ (lm & 7)) << 3)];
      }
#pragma unroll
      for (int mi = 0; mi < 4; ++mi)
        sa[mi] = __builtin_amdgcn_mfma_f32_16x16x32_bf16(ak[mi], qf[kk], sa[mi], 0, 0, 0);
    }

    float m4[4][4];
#pragma unroll
    for (int mi = 0; mi < 4; ++mi)
      *(float4*)m4[mi] = *(const float4*)&mask_s[d][mi * 16 + lq * 4];
#pragma unroll
    for (int mi = 0; mi < 4; ++mi)
#pragma unroll
      for (int r = 0; r < 4; ++r) {
        int kl = mi * 16 + lq * 4 + r;
        float p = __builtin_amdgcn_exp2f(
            fmaf(sa[mi][r], C0, bias_s[d][qq - kl + 63] + m4[mi][r]));
        sa[mi][r] = p;
        l_acc += p;
      }

#pragma unroll
    for (int mi = 0; mi < 4; ++mi) {
      bf16 h4[4];
#pragma unroll
      for (int r = 0; r < 4; ++r) h4[r] = __float2bfloat16(sa[mi][r]);
      int chunk = mi * 2 + (lq >> 1);
      *(uint2*)&Pl[qq * 64 + ((chunk ^ (lm & 7)) << 3) + ((lq & 1) << 2)] =
          *(uint2*)h4;
    }

#pragma unroll
    for (int kk2 = 0; kk2 < 2; ++kk2) {
      short8 pf = *(const short8*)&Pl[qq * 64 + (((kk2 * 4 + lq) ^ (lm & 7)) << 3)];
      short8 vf[4];
#pragma unroll
      for (int ni = 0; ni < 4; ++ni) {
        int rowv = ni * 16 + lm;
        vf[ni] = *(const short8*)&Vl[d][rowv * 64 + (((kk2 * 4 + lq) ^ (lm & 7)) << 3)];
      }
#pragma unroll
      for (int ni = 0; ni < 4; ++ni)
        acc_o[ni] = __builtin_amdgcn_mfma_f32_16x16x32_bf16(pf, vf[ni], acc_o[ni], 0, 0, 0);
    }
    __syncthreads();
  }

  l_acc += __shfl_xor(l_acc, 16);
  l_acc += __shfl_xor(l_acc, 32);
  float linv = 1.f / l_acc;
#pragma unroll
  for (int r = 0; r < 4; ++r) {
    float il = __shfl(linv, lq * 4 + r);
    int qx = w * 16 + lq * 4 + r;
    size_t rowbase = (size_t)(b * 1024 + q0 + qx) * 1024 + h * 64;
#pragma unroll
    for (int ni = 0; ni < 4; ++ni)
      ctx[rowbase + ni * 16 + lm] = __float2bfloat16(acc_o[ni][r] * il);
  }
}

// ---------------- residual + split-K reduce + bias + layernorm ----------------

template <int NS>
__global__ __launch_bounds__(256) void ln_resid(
    const float* __restrict__ xin, const bf16* __restrict__ part,
    const float* __restrict__ bias,
    const float* __restrict__ gw, const float* __restrict__ bw,
    float* __restrict__ outf, bf16* __restrict__ outb) {
  const int row = blockIdx.x, t = threadIdx.x;
  const size_t base = (size_t)row * 1024 + t * 4;
  float4 xv = *(const float4*)(xin + base);
  float4 bi = *(const float4*)(bias + t * 4);
  float v0 = xv.x + bi.x, v1 = xv.y + bi.y, v2 = xv.z + bi.z, v3 = xv.w + bi.w;
#pragma unroll
  for (int s = 0; s < NS; ++s) {
    const bf16* p = part + (size_t)s * 4194304 + base;
    ushort4 pv = *(const ushort4*)p;
    v0 += bf2f(pv.x); v1 += bf2f(pv.y); v2 += bf2f(pv.z); v3 += bf2f(pv.w);
  }
  float s1 = v0 + v1 + v2 + v3;
  float s2 = v0 * v0 + v1 * v1 + v2 * v2 + v3 * v3;
#pragma unroll
  for (int o = 1; o < 64; o <<= 1) {
    s1 += __shfl_xor(s1, o);
    s2 += __shfl_xor(s2, o);
  }
  __shared__ float red[8];
  const int w = t >> 6, l = t & 63;
  if (l == 0) { red[w] = s1; red[4 + w] = s2; }
  __syncthreads();
  float S1 = red[0] + red[1] + red[2] + red[3];
  float S2 = red[4] + red[5] + red[6] + red[7];
  float mean = S1 * (1.f / 1024.f);
  float var = S2 * (1.f / 1024.f) - mean * mean;
  float rstd = rsqrtf(var + 1e-5f);
  float4 gv = *(const float4*)(gw + t * 4);
  float4 bv = *(const float4*)(bw + t * 4);
  float o0 = (v0 - mean) * rstd * gv.x + bv.x;
  float o1 = (v1 - mean) * rstd * gv.y + bv.y;
  float o2 = (v2 - mean) * rstd * gv.z + bv.z;
  float o3 = (v3 - mean) * rstd * gv.w + bv.w;
  if (outf) {
    float4 ov = {o0, o1, o2, o3};
    *(float4*)(outf + base) = ov;
  }
  if (outb) {
    bf16 h4[4] = {__float2bfloat16(o0), __float2bfloat16(o1),
                  __float2bfloat16(o2), __float2bfloat16(o3)};
    *(uint2*)((unsigned short*)outb + base) = *(uint2*)h4;
  }
}

// ---------------- launcher ----------------

extern "C" void kernel_launch(void* const* d_in, const int* in_sizes, int n_in,
                              void* d_out, int out_size, void* d_ws, size_t ws_size,
                              hipStream_t stream) {
  (void)in_sizes; (void)n_in; (void)out_size; (void)ws_size;
  const float* x   = (const float*)d_in[0];
  const float* wq  = (const float*)d_in[1];
  const float* bq  = (const float*)d_in[2];
  const float* wk  = (const float*)d_in[3];
  const float* bk  = (const float*)d_in[4];
  const float* wv  = (const float*)d_in[5];
  const float* bv  = (const float*)d_in[6];
  const float* wo  = (const float*)d_in[7];
  const float* bo  = (const float*)d_in[8];
  const float* rel = (const float*)d_in[9];
  const float* g1  = (const float*)d_in[10];
  const float* be1 = (const float*)d_in[11];
  const float* w1  = (const float*)d_in[12];
  const float* b1  = (const float*)d_in[13];
  const float* w2  = (const float*)d_in[14];
  const float* b2  = (const float*)d_in[15];
  const float* g2  = (const float*)d_in[16];
  const float* be2 = (const float*)d_in[17];
  const int* mask  = (const int*)d_in[18];
  float* out = (float*)d_out;

  char* ws = (char*)d_ws;
  bf16*  xb      = (bf16*)(ws + 0);
  bf16*  wqkv_t  = (bf16*)(ws + 8388608);
  bf16*  wo_t    = (bf16*)(ws + 14680064);
  bf16*  w1_t    = (bf16*)(ws + 16777216);
  bf16*  ctx_b   = (bf16*)(ws + 25165824);
  bf16*  x1b     = (bf16*)(ws + 33554432);
  bf16*  qkv_b   = (bf16*)(ws + 41943040);
  bf16*  vtb     = (bf16*)(ws + 67108864);
  bf16*  part_wo = (bf16*)(ws + 41943040);   // aliases qkv_b+vtb (dead after flash)
  bf16*  h1      = (bf16*)(ws + 41943040);   // aliases qkv_b+vtb
  bf16*  part_ff = (bf16*)(ws + 0);          // aliases xb..ctx_b (all dead by FFN2)
  bf16*  w2_t    = (bf16*)(ws + 75497472);
  float* x1f     = (float*)(ws + 83886080);
  float* bqkv    = (float*)(ws + 100663296);

  prep_all<<<16385, 256, 0, stream>>>(x, bq, bk, bv, wq, wk, wv, wo, w1, w2,
                                      xb, bqkv, wqkv_t, wo_t, w1_t, w2_t);

  // QKV (+ fused V-transpose into vtb)
  gemm_bt<0, 1><<<dim3(32, 24), 256, 0, stream>>>(
      xb, wqkv_t, bqkv, qkv_b, vtb, 4096, 3072, 1024);
  flash_attn<<<dim3(8, 64), 512, 0, stream>>>(qkv_b, vtb, rel, mask, ctx_b);
  // WO: split-K=2 (512 blocks), KS=512
  gemm_bt_splitk<<<dim3(32, 8, 2), 256, 0, stream>>>(
      ctx_b, wo_t, part_wo, 4096, 1024, 1024, 512);
  ln_resid<2><<<4096, 256, 0, stream>>>(x, part_wo, bo, g1, be1, x1f, x1b);
  gemm_bt<1, 0><<<dim3(32, 32), 256, 0, stream>>>(
      x1b, w1_t, b1, h1, nullptr, 4096, 4096, 1024);
  // FFN2: split-K=2 (512 blocks), KS=2048
  gemm_bt_splitk<<<dim3(32, 8, 2), 256, 0, stream>>>(
      h1, w2_t, part_ff, 4096, 1024, 4096, 2048);
  ln_resid<2><<<4096, 256, 0, stream>>>(x1f, part_ff, b2, g2, be2, out, nullptr);
}

// Round 11
// 319.749 us; speedup vs baseline: 1.0507x; 1.0107x over previous
//
#include <hip/hip_runtime.h>
#include <hip/hip_bf16.h>

typedef __hip_bfloat16 bf16;
typedef __attribute__((ext_vector_type(8))) short short8;
typedef __attribute__((ext_vector_type(4))) float f32x4;

#define LOG2E 1.4426950408889634f

typedef const __attribute__((address_space(1))) void* gptr_t;
typedef __attribute__((address_space(3))) void* sptr_t;

__device__ __forceinline__ void async16(void* lds, const void* g) {
  __builtin_amdgcn_global_load_lds((gptr_t)g, (sptr_t)lds, 16, 0, 0);
}

__device__ __forceinline__ float bf2f(unsigned short u) {
  union { unsigned int i; float f; } c; c.i = ((unsigned int)u) << 16; return c.f;
}

// ---------------- merged prep: cast x + concat bias + 6 transposes ----------------

__global__ __launch_bounds__(256) void prep_all(
    const float* __restrict__ x, const float* __restrict__ bq,
    const float* __restrict__ bk, const float* __restrict__ bv,
    const float* __restrict__ wq, const float* __restrict__ wk,
    const float* __restrict__ wv, const float* __restrict__ wo,
    const float* __restrict__ w1, const float* __restrict__ w2,
    bf16* __restrict__ xb, float* __restrict__ bqkv,
    bf16* __restrict__ dqkv, bf16* __restrict__ dwo,
    bf16* __restrict__ dw1, bf16* __restrict__ dw2) {
  const int bid = blockIdx.x;
  if (bid < 4096) {
    int i = (bid * 256 + threadIdx.x) * 4;
    float4 v = *(const float4*)(x + i);
    bf16 h4[4] = {__float2bfloat16(v.x), __float2bfloat16(v.y),
                  __float2bfloat16(v.z), __float2bfloat16(v.w)};
    *(uint2*)((unsigned short*)xb + i) = *(uint2*)h4;
    return;
  }
  if (bid == 16384) {
#pragma unroll
    for (int j = 0; j < 12; ++j) {
      int i = j * 256 + threadIdx.x;
      bqkv[i] = (i < 1024) ? bq[i] : (i < 2048 ? bk[i - 1024] : bv[i - 2048]);
    }
    return;
  }
  __shared__ float tl[32][33];
  const int tid = bid - 4096;
  const float* s;
  bf16* d;
  int NN, KK, n0, k0;
  if (tid < 4096) {
    int m = tid >> 10, tile = tid & 1023;
    s = m == 0 ? wq : m == 1 ? wk : m == 2 ? wv : wo;
    d = m < 3 ? dqkv + (size_t)m * 1024 * 1024 : dwo;
    NN = 1024; KK = 1024;
    n0 = (tile & 31) * 32; k0 = (tile >> 5) * 32;
  } else if (tid < 8192) {
    int tile = tid - 4096;
    s = w1; d = dw1; NN = 4096; KK = 1024;
    n0 = (tile & 127) * 32; k0 = (tile >> 7) * 32;
  } else {
    int tile = tid - 8192;
    s = w2; d = dw2; NN = 1024; KK = 4096;
    n0 = (tile & 31) * 32; k0 = (tile >> 5) * 32;
  }
  const int tx = threadIdx.x & 31, ty = threadIdx.x >> 5;
#pragma unroll
  for (int j = 0; j < 4; ++j)
    tl[ty + j * 8][tx] = s[(size_t)(k0 + ty + j * 8) * NN + n0 + tx];
  __syncthreads();
#pragma unroll
  for (int j = 0; j < 4; ++j)
    d[(size_t)(n0 + ty + j * 8) * KK + k0 + tx] =
        __float2bfloat16(tl[tx][ty + j * 8]);
}

// ---------------- GEMM: C[M][N] = A[M][K] * Bt[N][K]^T + bias ----------------
// BK=64 double-buffer, ONE barrier per K-tile (measured best). blockIdx.x =
// M-tile (32%8==0) => A-slab pinned per XCD. chunk^(row&7) swizzle: 0 conflicts.

template <int RELU, int VT>
__global__ __launch_bounds__(256) void gemm_bt(
    const bf16* __restrict__ A, const bf16* __restrict__ Bt,
    const float* __restrict__ bias, bf16* __restrict__ C,
    bf16* __restrict__ vt, int M, int N, int K) {
  __shared__ bf16 As[2][128 * 64];
  __shared__ bf16 Bs[2][128 * 64];
  const int t = threadIdx.x;
  const int w = t >> 6, l = t & 63;
  const int m0 = blockIdx.x * 128, n0 = blockIdx.y * 128;
  const int wr = (w >> 1) * 64, wc = (w & 1) * 64;
  const int srow = l >> 3, scol = l & 7;
  const int lm = l & 15, lq = l >> 4;

  f32x4 acc[4][4];
#pragma unroll
  for (int i = 0; i < 4; ++i)
#pragma unroll
    for (int j = 0; j < 4; ++j) acc[i][j] = (f32x4){0.f, 0.f, 0.f, 0.f};

  auto stage = [&](int k0, int d) {
#pragma unroll
    for (int p = 0; p < 4; ++p) {
      int row = p * 32 + w * 8 + srow;
      int gc = scol ^ (row & 7);
      async16(&As[d][(p * 32 + w * 8) * 64], A + (size_t)(m0 + row) * K + k0 + gc * 8);
      async16(&Bs[d][(p * 32 + w * 8) * 64], Bt + (size_t)(n0 + row) * K + k0 + gc * 8);
    }
  };

  stage(0, 0);
  const int niter = K >> 6;
  for (int it = 0; it < niter; ++it) {
    const int d = it & 1;
    __syncthreads();  // drains stage(d) [vmcnt] + prev frag reads [lgkm]
    short8 af[2][4], bfr[2][4];
#pragma unroll
    for (int kk = 0; kk < 2; ++kk)
#pragma unroll
      for (int mi = 0; mi < 4; ++mi) {
        int rowa = wr + mi * 16 + lm;
        af[kk][mi] = *(const short8*)&As[d][rowa * 64 + (((kk * 4 + lq) ^ (rowa & 7)) << 3)];
        int rowb = wc + mi * 16 + lm;
        bfr[kk][mi] = *(const short8*)&Bs[d][rowb * 64 + (((kk * 4 + lq) ^ (rowb & 7)) << 3)];
      }
    if (it + 1 < niter) stage((it + 1) << 6, d ^ 1);
#pragma unroll
    for (int kk = 0; kk < 2; ++kk)
#pragma unroll
      for (int mi = 0; mi < 4; ++mi)
#pragma unroll
        for (int ni = 0; ni < 4; ++ni)
          acc[mi][ni] = __builtin_amdgcn_mfma_f32_16x16x32_bf16(
              af[kk][mi], bfr[kk][ni], acc[mi][ni], 0, 0, 0);
  }

#pragma unroll
  for (int mi = 0; mi < 4; ++mi)
#pragma unroll
    for (int ni = 0; ni < 4; ++ni) {
      int col = n0 + wc + ni * 16 + lm;
      int row0 = m0 + wr + mi * 16 + lq * 4;
      float bv = bias[col];
      float v[4];
#pragma unroll
      for (int r = 0; r < 4; ++r) {
        v[r] = acc[mi][ni][r] + bv;
        if (RELU) v[r] = fmaxf(v[r], 0.f);
        C[(size_t)(row0 + r) * N + col] = __float2bfloat16(v[r]);
      }
      if (VT && col >= 2048) {  // also store V transposed: vt[bh*64+dk][s]
        int vcol = col - 2048;
        int bh = (row0 >> 10) * 16 + (vcol >> 6);
        int dk = vcol & 63;
        int s = row0 & 1023;
        bf16 h4[4] = {__float2bfloat16(v[0]), __float2bfloat16(v[1]),
                      __float2bfloat16(v[2]), __float2bfloat16(v[3])};
        *(uint2*)&vt[((size_t)bh * 64 + dk) * 1024 + s] = *(uint2*)h4;
      }
    }
}

// split-K variant: blockIdx.z = split s; writes raw partial to P + s*M*N.
__global__ __launch_bounds__(256) void gemm_bt_splitk(
    const bf16* __restrict__ A, const bf16* __restrict__ Bt,
    bf16* __restrict__ P, int M, int N, int lda, int KS) {
  __shared__ bf16 As[2][128 * 64];
  __shared__ bf16 Bs[2][128 * 64];
  const int t = threadIdx.x;
  const int w = t >> 6, l = t & 63;
  const int m0 = blockIdx.x * 128, n0 = blockIdx.y * 128;
  const int kstart = blockIdx.z * KS;
  const int wr = (w >> 1) * 64, wc = (w & 1) * 64;
  const int srow = l >> 3, scol = l & 7;
  const int lm = l & 15, lq = l >> 4;

  f32x4 acc[4][4];
#pragma unroll
  for (int i = 0; i < 4; ++i)
#pragma unroll
    for (int j = 0; j < 4; ++j) acc[i][j] = (f32x4){0.f, 0.f, 0.f, 0.f};

  auto stage = [&](int k0, int d) {
#pragma unroll
    for (int p = 0; p < 4; ++p) {
      int row = p * 32 + w * 8 + srow;
      int gc = scol ^ (row & 7);
      async16(&As[d][(p * 32 + w * 8) * 64], A + (size_t)(m0 + row) * lda + k0 + gc * 8);
      async16(&Bs[d][(p * 32 + w * 8) * 64], Bt + (size_t)(n0 + row) * lda + k0 + gc * 8);
    }
  };

  stage(kstart, 0);
  const int niter = KS >> 6;
  for (int it = 0; it < niter; ++it) {
    const int d = it & 1;
    __syncthreads();
    short8 af[2][4], bfr[2][4];
#pragma unroll
    for (int kk = 0; kk < 2; ++kk)
#pragma unroll
      for (int mi = 0; mi < 4; ++mi) {
        int rowa = wr + mi * 16 + lm;
        af[kk][mi] = *(const short8*)&As[d][rowa * 64 + (((kk * 4 + lq) ^ (rowa & 7)) << 3)];
        int rowb = wc + mi * 16 + lm;
        bfr[kk][mi] = *(const short8*)&Bs[d][rowb * 64 + (((kk * 4 + lq) ^ (rowb & 7)) << 3)];
      }
    if (it + 1 < niter) stage(kstart + ((it + 1) << 6), d ^ 1);
#pragma unroll
    for (int kk = 0; kk < 2; ++kk)
#pragma unroll
      for (int mi = 0; mi < 4; ++mi)
#pragma unroll
        for (int ni = 0; ni < 4; ++ni)
          acc[mi][ni] = __builtin_amdgcn_mfma_f32_16x16x32_bf16(
              af[kk][mi], bfr[kk][ni], acc[mi][ni], 0, 0, 0);
  }
  bf16* Pz = P + (size_t)blockIdx.z * M * N;
#pragma unroll
  for (int mi = 0; mi < 4; ++mi)
#pragma unroll
    for (int r = 0; r < 4; ++r) {
      int row = m0 + wr + mi * 16 + lq * 4 + r;
#pragma unroll
      for (int ni = 0; ni < 4; ++ni) {
        int col = n0 + wc + ni * 16 + lm;
        Pz[(size_t)row * N + col] = __float2bfloat16(acc[mi][ni][r]);
      }
    }
}

// ---------------- flash attention (bounded-score softmax, q-tile=64) ----------------
// 256 threads = 4 waves, each wave owns 16 q rows (wave-private softmax/P).
// LDS ~42 KB -> 3 blocks/CU (vs 2 at the 128-q/512-thread shape). grid 16x64.

__global__ __launch_bounds__(256, 3) void flash_attn(
    const bf16* __restrict__ qkv, const bf16* __restrict__ vt,
    const float* __restrict__ rel, const int* __restrict__ mask,
    bf16* __restrict__ ctx) {
  __shared__ bf16 Kl[2][64 * 64];
  __shared__ bf16 Vl[2][64 * 64];
  __shared__ bf16 Pl[64 * 64];  // Q staging in prologue, then P
  __shared__ float bias_s[2][128];
  __shared__ float mask_s[2][64];

  const int t = threadIdx.x;
  const int w = t >> 6, l = t & 63;
  const int lm = l & 15, lq = l >> 4;
  const int qt = blockIdx.x, bh = blockIdx.y;
  const int b = bh >> 4, h = bh & 15;
  const int q0 = qt * 64;
  const int srow = l >> 3;
  const int gc = (l & 7) ^ srow;
  const int qq = w * 16 + lm;

  auto stage = [&](int d, int k0n) {
#pragma unroll
    for (int p = 0; p < 2; ++p) {
      int rbase = w * 16 + p * 8;
      async16(&Kl[d][rbase * 64],
              qkv + (size_t)(b * 1024 + k0n + rbase + srow) * 3072 + 1024 + h * 64 + gc * 8);
      async16(&Vl[d][rbase * 64],
              vt + ((size_t)bh * 64 + rbase + srow) * 1024 + k0n + gc * 8);
    }
    if (t < 127) bias_s[d][t] = rel[(q0 - k0n + 960 + t) * 16 + h] * LOG2E;
    if (t < 64) mask_s[d][t] = (mask[b * 1024 + k0n + t] == 0) ? -1.44e9f : 0.f;
  };

#pragma unroll
  for (int p = 0; p < 2; ++p) {
    int rbase = w * 16 + p * 8;
    async16(&Pl[rbase * 64],
            qkv + (size_t)(b * 1024 + q0 + rbase + srow) * 3072 + h * 64 + gc * 8);
  }
  stage(0, 0);
  __syncthreads();

  short8 qf[2];
#pragma unroll
  for (int kk = 0; kk < 2; ++kk)
    qf[kk] = *(const short8*)&Pl[qq * 64 + (((kk * 4 + lq) ^ (lm & 7)) << 3)];
  __syncthreads();

  float l_acc = 0.f;
  f32x4 acc_o[4];
#pragma unroll
  for (int j = 0; j < 4; ++j) acc_o[j] = (f32x4){0.f, 0.f, 0.f, 0.f};

  const float C0 = 0.125f * LOG2E;

  for (int kt = 0; kt < 16; ++kt) {
    const int d = kt & 1;
    if (kt < 15) stage(d ^ 1, (kt + 1) * 64);

    // S^T[sk][q] = K·Q^T
    f32x4 sa[4];
#pragma unroll
    for (int i = 0; i < 4; ++i) sa[i] = (f32x4){0.f, 0.f, 0.f, 0.f};
#pragma unroll
    for (int kk = 0; kk < 2; ++kk) {
      short8 ak[4];
#pragma unroll
      for (int mi = 0; mi < 4; ++mi) {
        int row = mi * 16 + lm;
        ak[mi] = *(const short8*)&Kl[d][row * 64 + (((kk * 4 + lq) ^ (lm & 7)) << 3)];
      }
#pragma unroll
      for (int mi = 0; mi < 4; ++mi)
        sa[mi] = __builtin_amdgcn_mfma_f32_16x16x32_bf16(ak[mi], qf[kk], sa[mi], 0, 0, 0);
    }

    // p = exp2(s*C0 + bias + mask); bounded scores -> no running max
    float m4[4][4];
#pragma unroll
    for (int mi = 0; mi < 4; ++mi)
      *(float4*)m4[mi] = *(const float4*)&mask_s[d][mi * 16 + lq * 4];
#pragma unroll
    for (int mi = 0; mi < 4; ++mi)
#pragma unroll
      for (int r = 0; r < 4; ++r) {
        int kl = mi * 16 + lq * 4 + r;
        float p = __builtin_amdgcn_exp2f(
            fmaf(sa[mi][r], C0, bias_s[d][qq - kl + 63] + m4[mi][r]));
        sa[mi][r] = p;
        l_acc += p;
      }

#pragma unroll
    for (int mi = 0; mi < 4; ++mi) {
      bf16 h4[4];
#pragma unroll
      for (int r = 0; r < 4; ++r) h4[r] = __float2bfloat16(sa[mi][r]);
      int chunk = mi * 2 + (lq >> 1);
      *(uint2*)&Pl[qq * 64 + ((chunk ^ (lm & 7)) << 3) + ((lq & 1) << 2)] =
          *(uint2*)h4;
    }

#pragma unroll
    for (int kk2 = 0; kk2 < 2; ++kk2) {
      short8 pf = *(const short8*)&Pl[qq * 64 + (((kk2 * 4 + lq) ^ (lm & 7)) << 3)];
      short8 vf[4];
#pragma unroll
      for (int ni = 0; ni < 4; ++ni) {
        int rowv = ni * 16 + lm;
        vf[ni] = *(const short8*)&Vl[d][rowv * 64 + (((kk2 * 4 + lq) ^ (lm & 7)) << 3)];
      }
#pragma unroll
      for (int ni = 0; ni < 4; ++ni)
        acc_o[ni] = __builtin_amdgcn_mfma_f32_16x16x32_bf16(pf, vf[ni], acc_o[ni], 0, 0, 0);
    }
    __syncthreads();
  }

  l_acc += __shfl_xor(l_acc, 16);
  l_acc += __shfl_xor(l_acc, 32);
  float linv = 1.f / l_acc;
#pragma unroll
  for (int r = 0; r < 4; ++r) {
    float il = __shfl(linv, lq * 4 + r);
    int qx = w * 16 + lq * 4 + r;
    size_t rowbase = (size_t)(b * 1024 + q0 + qx) * 1024 + h * 64;
#pragma unroll
    for (int ni = 0; ni < 4; ++ni)
      ctx[rowbase + ni * 16 + lm] = __float2bfloat16(acc_o[ni][r] * il);
  }
}

// ---------------- residual + split-K reduce + bias + layernorm ----------------
// RT = residual dtype (float for x, bf16 for x1).

template <typename RT, int NS>
__global__ __launch_bounds__(256) void ln_resid(
    const RT* __restrict__ xin, const bf16* __restrict__ part,
    const float* __restrict__ bias,
    const float* __restrict__ gw, const float* __restrict__ bw,
    float* __restrict__ outf, bf16* __restrict__ outb) {
  const int row = blockIdx.x, t = threadIdx.x;
  const size_t base = (size_t)row * 1024 + t * 4;
  float v0, v1, v2, v3;
  if constexpr (sizeof(RT) == 4) {
    float4 xv = *(const float4*)(xin + base);
    v0 = xv.x; v1 = xv.y; v2 = xv.z; v3 = xv.w;
  } else {
    ushort4 xv = *(const ushort4*)((const unsigned short*)xin + base);
    v0 = bf2f(xv.x); v1 = bf2f(xv.y); v2 = bf2f(xv.z); v3 = bf2f(xv.w);
  }
  float4 bi = *(const float4*)(bias + t * 4);
  v0 += bi.x; v1 += bi.y; v2 += bi.z; v3 += bi.w;
#pragma unroll
  for (int s = 0; s < NS; ++s) {
    const bf16* p = part + (size_t)s * 4194304 + base;
    ushort4 pv = *(const ushort4*)p;
    v0 += bf2f(pv.x); v1 += bf2f(pv.y); v2 += bf2f(pv.z); v3 += bf2f(pv.w);
  }
  float s1 = v0 + v1 + v2 + v3;
  float s2 = v0 * v0 + v1 * v1 + v2 * v2 + v3 * v3;
#pragma unroll
  for (int o = 1; o < 64; o <<= 1) {
    s1 += __shfl_xor(s1, o);
    s2 += __shfl_xor(s2, o);
  }
  __shared__ float red[8];
  const int w = t >> 6, l = t & 63;
  if (l == 0) { red[w] = s1; red[4 + w] = s2; }
  __syncthreads();
  float S1 = red[0] + red[1] + red[2] + red[3];
  float S2 = red[4] + red[5] + red[6] + red[7];
  float mean = S1 * (1.f / 1024.f);
  float var = S2 * (1.f / 1024.f) - mean * mean;
  float rstd = rsqrtf(var + 1e-5f);
  float4 gv = *(const float4*)(gw + t * 4);
  float4 bv = *(const float4*)(bw + t * 4);
  float o0 = (v0 - mean) * rstd * gv.x + bv.x;
  float o1 = (v1 - mean) * rstd * gv.y + bv.y;
  float o2 = (v2 - mean) * rstd * gv.z + bv.z;
  float o3 = (v3 - mean) * rstd * gv.w + bv.w;
  if (outf) {
    float4 ov = {o0, o1, o2, o3};
    *(float4*)(outf + base) = ov;
  }
  if (outb) {
    bf16 h4[4] = {__float2bfloat16(o0), __float2bfloat16(o1),
                  __float2bfloat16(o2), __float2bfloat16(o3)};
    *(uint2*)((unsigned short*)outb + base) = *(uint2*)h4;
  }
}

// ---------------- launcher ----------------

extern "C" void kernel_launch(void* const* d_in, const int* in_sizes, int n_in,
                              void* d_out, int out_size, void* d_ws, size_t ws_size,
                              hipStream_t stream) {
  (void)in_sizes; (void)n_in; (void)out_size; (void)ws_size;
  const float* x   = (const float*)d_in[0];
  const float* wq  = (const float*)d_in[1];
  const float* bq  = (const float*)d_in[2];
  const float* wk  = (const float*)d_in[3];
  const float* bk  = (const float*)d_in[4];
  const float* wv  = (const float*)d_in[5];
  const float* bv  = (const float*)d_in[6];
  const float* wo  = (const float*)d_in[7];
  const float* bo  = (const float*)d_in[8];
  const float* rel = (const float*)d_in[9];
  const float* g1  = (const float*)d_in[10];
  const float* be1 = (const float*)d_in[11];
  const float* w1  = (const float*)d_in[12];
  const float* b1  = (const float*)d_in[13];
  const float* w2  = (const float*)d_in[14];
  const float* b2  = (const float*)d_in[15];
  const float* g2  = (const float*)d_in[16];
  const float* be2 = (const float*)d_in[17];
  const int* mask  = (const int*)d_in[18];
  float* out = (float*)d_out;

  char* ws = (char*)d_ws;
  bf16*  xb      = (bf16*)(ws + 0);
  bf16*  wqkv_t  = (bf16*)(ws + 8388608);
  bf16*  wo_t    = (bf16*)(ws + 14680064);
  bf16*  w1_t    = (bf16*)(ws + 16777216);
  bf16*  ctx_b   = (bf16*)(ws + 25165824);
  bf16*  x1b     = (bf16*)(ws + 33554432);
  bf16*  qkv_b   = (bf16*)(ws + 41943040);
  bf16*  vtb     = (bf16*)(ws + 67108864);
  bf16*  part_wo = (bf16*)(ws + 41943040);   // aliases qkv_b+vtb (dead after flash)
  bf16*  h1      = (bf16*)(ws + 41943040);   // aliases qkv_b+vtb
  bf16*  part_ff = (bf16*)(ws + 0);          // aliases xb..ctx_b (all dead by FFN2)
  bf16*  w2_t    = (bf16*)(ws + 75497472);
  float* bqkv    = (float*)(ws + 100663296);

  prep_all<<<16385, 256, 0, stream>>>(x, bq, bk, bv, wq, wk, wv, wo, w1, w2,
                                      xb, bqkv, wqkv_t, wo_t, w1_t, w2_t);

  // QKV (+ fused V-transpose into vtb)
  gemm_bt<0, 1><<<dim3(32, 24), 256, 0, stream>>>(
      xb, wqkv_t, bqkv, qkv_b, vtb, 4096, 3072, 1024);
  flash_attn<<<dim3(16, 64), 256, 0, stream>>>(qkv_b, vtb, rel, mask, ctx_b);
  // WO: split-K=2 (512 blocks), KS=512
  gemm_bt_splitk<<<dim3(32, 8, 2), 256, 0, stream>>>(
      ctx_b, wo_t, part_wo, 4096, 1024, 1024, 512);
  ln_resid<float, 2><<<4096, 256, 0, stream>>>(x, part_wo, bo, g1, be1, nullptr, x1b);
  gemm_bt<1, 0><<<dim3(32, 32), 256, 0, stream>>>(
      x1b, w1_t, b1, h1, nullptr, 4096, 4096, 1024);
  // FFN2: split-K=2 (512 blocks), KS=2048
  gemm_bt_splitk<<<dim3(32, 8, 2), 256, 0, stream>>>(
      h1, w2_t, part_ff, 4096, 1024, 4096, 2048);
  ln_resid<bf16, 2><<<4096, 256, 0, stream>>>(x1b, part_ff, b2, g2, be2, out, nullptr);
}

// Round 12
// 316.247 us; speedup vs baseline: 1.0623x; 1.0111x over previous
//
#include <hip/hip_runtime.h>
#include <hip/hip_bf16.h>

typedef __hip_bfloat16 bf16;
typedef __attribute__((ext_vector_type(8))) short short8;
typedef __attribute__((ext_vector_type(4))) float f32x4;

#define LOG2E 1.4426950408889634f

typedef const __attribute__((address_space(1))) void* gptr_t;
typedef __attribute__((address_space(3))) void* sptr_t;

__device__ __forceinline__ void async16(void* lds, const void* g) {
  __builtin_amdgcn_global_load_lds((gptr_t)g, (sptr_t)lds, 16, 0, 0);
}

__device__ __forceinline__ float bf2f(unsigned short u) {
  union { unsigned int i; float f; } c; c.i = ((unsigned int)u) << 16; return c.f;
}

// ---------------- merged prep: cast x + concat bias + 6 transposes ----------------

__global__ __launch_bounds__(256) void prep_all(
    const float* __restrict__ x, const float* __restrict__ bq,
    const float* __restrict__ bk, const float* __restrict__ bv,
    const float* __restrict__ wq, const float* __restrict__ wk,
    const float* __restrict__ wv, const float* __restrict__ wo,
    const float* __restrict__ w1, const float* __restrict__ w2,
    bf16* __restrict__ xb, float* __restrict__ bqkv,
    bf16* __restrict__ dqkv, bf16* __restrict__ dwo,
    bf16* __restrict__ dw1, bf16* __restrict__ dw2) {
  const int bid = blockIdx.x;
  if (bid < 4096) {
    int i = (bid * 256 + threadIdx.x) * 4;
    float4 v = *(const float4*)(x + i);
    bf16 h4[4] = {__float2bfloat16(v.x), __float2bfloat16(v.y),
                  __float2bfloat16(v.z), __float2bfloat16(v.w)};
    *(uint2*)((unsigned short*)xb + i) = *(uint2*)h4;
    return;
  }
  if (bid == 16384) {
#pragma unroll
    for (int j = 0; j < 12; ++j) {
      int i = j * 256 + threadIdx.x;
      bqkv[i] = (i < 1024) ? bq[i] : (i < 2048 ? bk[i - 1024] : bv[i - 2048]);
    }
    return;
  }
  __shared__ float tl[32][33];
  const int tid = bid - 4096;
  const float* s;
  bf16* d;
  int NN, KK, n0, k0;
  if (tid < 4096) {
    int m = tid >> 10, tile = tid & 1023;
    s = m == 0 ? wq : m == 1 ? wk : m == 2 ? wv : wo;
    d = m < 3 ? dqkv + (size_t)m * 1024 * 1024 : dwo;
    NN = 1024; KK = 1024;
    n0 = (tile & 31) * 32; k0 = (tile >> 5) * 32;
  } else if (tid < 8192) {
    int tile = tid - 4096;
    s = w1; d = dw1; NN = 4096; KK = 1024;
    n0 = (tile & 127) * 32; k0 = (tile >> 7) * 32;
  } else {
    int tile = tid - 8192;
    s = w2; d = dw2; NN = 1024; KK = 4096;
    n0 = (tile & 31) * 32; k0 = (tile >> 5) * 32;
  }
  const int tx = threadIdx.x & 31, ty = threadIdx.x >> 5;
#pragma unroll
  for (int j = 0; j < 4; ++j)
    tl[ty + j * 8][tx] = s[(size_t)(k0 + ty + j * 8) * NN + n0 + tx];
  __syncthreads();
#pragma unroll
  for (int j = 0; j < 4; ++j)
    d[(size_t)(n0 + ty + j * 8) * KK + k0 + tx] =
        __float2bfloat16(tl[tx][ty + j * 8]);
}

// ---------------- GEMM: C[M][N] = A[M][K] * Bt[N][K]^T + bias ----------------
// BK=64 double-buffer, ONE barrier per K-tile (measured best). blockIdx.x =
// M-tile (32%8==0) => A-slab pinned per XCD. chunk^(row&7) swizzle: 0 conflicts.

template <int RELU, int VT>
__global__ __launch_bounds__(256) void gemm_bt(
    const bf16* __restrict__ A, const bf16* __restrict__ Bt,
    const float* __restrict__ bias, bf16* __restrict__ C,
    bf16* __restrict__ vt, int M, int N, int K) {
  __shared__ bf16 As[2][128 * 64];
  __shared__ bf16 Bs[2][128 * 64];
  const int t = threadIdx.x;
  const int w = t >> 6, l = t & 63;
  const int m0 = blockIdx.x * 128, n0 = blockIdx.y * 128;
  const int wr = (w >> 1) * 64, wc = (w & 1) * 64;
  const int srow = l >> 3, scol = l & 7;
  const int lm = l & 15, lq = l >> 4;

  f32x4 acc[4][4];
#pragma unroll
  for (int i = 0; i < 4; ++i)
#pragma unroll
    for (int j = 0; j < 4; ++j) acc[i][j] = (f32x4){0.f, 0.f, 0.f, 0.f};

  auto stage = [&](int k0, int d) {
#pragma unroll
    for (int p = 0; p < 4; ++p) {
      int row = p * 32 + w * 8 + srow;
      int gc = scol ^ (row & 7);
      async16(&As[d][(p * 32 + w * 8) * 64], A + (size_t)(m0 + row) * K + k0 + gc * 8);
      async16(&Bs[d][(p * 32 + w * 8) * 64], Bt + (size_t)(n0 + row) * K + k0 + gc * 8);
    }
  };

  stage(0, 0);
  const int niter = K >> 6;
  for (int it = 0; it < niter; ++it) {
    const int d = it & 1;
    __syncthreads();  // drains stage(d) [vmcnt] + prev frag reads [lgkm]
    short8 af[2][4], bfr[2][4];
#pragma unroll
    for (int kk = 0; kk < 2; ++kk)
#pragma unroll
      for (int mi = 0; mi < 4; ++mi) {
        int rowa = wr + mi * 16 + lm;
        af[kk][mi] = *(const short8*)&As[d][rowa * 64 + (((kk * 4 + lq) ^ (rowa & 7)) << 3)];
        int rowb = wc + mi * 16 + lm;
        bfr[kk][mi] = *(const short8*)&Bs[d][rowb * 64 + (((kk * 4 + lq) ^ (rowb & 7)) << 3)];
      }
    if (it + 1 < niter) stage((it + 1) << 6, d ^ 1);
#pragma unroll
    for (int kk = 0; kk < 2; ++kk)
#pragma unroll
      for (int mi = 0; mi < 4; ++mi)
#pragma unroll
        for (int ni = 0; ni < 4; ++ni)
          acc[mi][ni] = __builtin_amdgcn_mfma_f32_16x16x32_bf16(
              af[kk][mi], bfr[kk][ni], acc[mi][ni], 0, 0, 0);
  }

#pragma unroll
  for (int mi = 0; mi < 4; ++mi)
#pragma unroll
    for (int ni = 0; ni < 4; ++ni) {
      int col = n0 + wc + ni * 16 + lm;
      int row0 = m0 + wr + mi * 16 + lq * 4;
      float bv = bias[col];
      float v[4];
#pragma unroll
      for (int r = 0; r < 4; ++r) {
        v[r] = acc[mi][ni][r] + bv;
        if (RELU) v[r] = fmaxf(v[r], 0.f);
        C[(size_t)(row0 + r) * N + col] = __float2bfloat16(v[r]);
      }
      if (VT && col >= 2048) {  // also store V transposed: vt[bh*64+dk][s]
        int vcol = col - 2048;
        int bh = (row0 >> 10) * 16 + (vcol >> 6);
        int dk = vcol & 63;
        int s = row0 & 1023;
        bf16 h4[4] = {__float2bfloat16(v[0]), __float2bfloat16(v[1]),
                      __float2bfloat16(v[2]), __float2bfloat16(v[3])};
        *(uint2*)&vt[((size_t)bh * 64 + dk) * 1024 + s] = *(uint2*)h4;
      }
    }
}

// split-K variant: blockIdx.z = split s; writes raw partial to P + s*M*N.
__global__ __launch_bounds__(256) void gemm_bt_splitk(
    const bf16* __restrict__ A, const bf16* __restrict__ Bt,
    bf16* __restrict__ P, int M, int N, int lda, int KS) {
  __shared__ bf16 As[2][128 * 64];
  __shared__ bf16 Bs[2][128 * 64];
  const int t = threadIdx.x;
  const int w = t >> 6, l = t & 63;
  const int m0 = blockIdx.x * 128, n0 = blockIdx.y * 128;
  const int kstart = blockIdx.z * KS;
  const int wr = (w >> 1) * 64, wc = (w & 1) * 64;
  const int srow = l >> 3, scol = l & 7;
  const int lm = l & 15, lq = l >> 4;

  f32x4 acc[4][4];
#pragma unroll
  for (int i = 0; i < 4; ++i)
#pragma unroll
    for (int j = 0; j < 4; ++j) acc[i][j] = (f32x4){0.f, 0.f, 0.f, 0.f};

  auto stage = [&](int k0, int d) {
#pragma unroll
    for (int p = 0; p < 4; ++p) {
      int row = p * 32 + w * 8 + srow;
      int gc = scol ^ (row & 7);
      async16(&As[d][(p * 32 + w * 8) * 64], A + (size_t)(m0 + row) * lda + k0 + gc * 8);
      async16(&Bs[d][(p * 32 + w * 8) * 64], Bt + (size_t)(n0 + row) * lda + k0 + gc * 8);
    }
  };

  stage(kstart, 0);
  const int niter = KS >> 6;
  for (int it = 0; it < niter; ++it) {
    const int d = it & 1;
    __syncthreads();
    short8 af[2][4], bfr[2][4];
#pragma unroll
    for (int kk = 0; kk < 2; ++kk)
#pragma unroll
      for (int mi = 0; mi < 4; ++mi) {
        int rowa = wr + mi * 16 + lm;
        af[kk][mi] = *(const short8*)&As[d][rowa * 64 + (((kk * 4 + lq) ^ (rowa & 7)) << 3)];
        int rowb = wc + mi * 16 + lm;
        bfr[kk][mi] = *(const short8*)&Bs[d][rowb * 64 + (((kk * 4 + lq) ^ (rowb & 7)) << 3)];
      }
    if (it + 1 < niter) stage(kstart + ((it + 1) << 6), d ^ 1);
#pragma unroll
    for (int kk = 0; kk < 2; ++kk)
#pragma unroll
      for (int mi = 0; mi < 4; ++mi)
#pragma unroll
        for (int ni = 0; ni < 4; ++ni)
          acc[mi][ni] = __builtin_amdgcn_mfma_f32_16x16x32_bf16(
              af[kk][mi], bfr[kk][ni], acc[mi][ni], 0, 0, 0);
  }
  bf16* Pz = P + (size_t)blockIdx.z * M * N;
#pragma unroll
  for (int mi = 0; mi < 4; ++mi)
#pragma unroll
    for (int r = 0; r < 4; ++r) {
      int row = m0 + wr + mi * 16 + lq * 4 + r;
#pragma unroll
      for (int ni = 0; ni < 4; ++ni) {
        int col = n0 + wc + ni * 16 + lm;
        Pz[(size_t)row * N + col] = __float2bfloat16(acc[mi][ni][r]);
      }
    }
}

// ---------------- flash attention (bounded softmax, split-S) ----------------
// q-tile=128, 512 threads = 8 waves (measured-best shape). blockIdx.z splits
// the S dimension in 2: block z accumulates UNNORMALIZED O_z and l_z over its
// 8 k-tiles (no rescale needed -> partials are associative). combine_ctx sums
// partials and divides. Halves the per-block serial chain, doubles blocks.

__global__ __launch_bounds__(512, 4) void flash_attn(
    const bf16* __restrict__ qkv, const bf16* __restrict__ vt,
    const float* __restrict__ rel, const int* __restrict__ mask,
    bf16* __restrict__ ctx_part, float* __restrict__ lpart) {
  __shared__ bf16 Kl[2][64 * 64];
  __shared__ bf16 Vl[2][64 * 64];
  __shared__ bf16 Pl[128 * 64];
  __shared__ float bias_s[2][192];
  __shared__ float mask_s[2][64];

  const int t = threadIdx.x;
  const int w = t >> 6, l = t & 63;
  const int lm = l & 15, lq = l >> 4;
  const int qt = blockIdx.x, bh = blockIdx.y, z = blockIdx.z;
  const int b = bh >> 4, h = bh & 15;
  const int q0 = qt * 128;
  const int kt0 = z * 8;
  const int srow = l >> 3;
  const int gc = (l & 7) ^ srow;
  const int qq = w * 16 + lm;

  auto stage = [&](int d, int k0n) {
    async16(&Kl[d][w * 8 * 64],
            qkv + (size_t)(b * 1024 + k0n + w * 8 + srow) * 3072 + 1024 + h * 64 + gc * 8);
    async16(&Vl[d][w * 8 * 64],
            vt + ((size_t)bh * 64 + w * 8 + srow) * 1024 + k0n + gc * 8);
    if (t < 191) bias_s[d][t] = rel[(q0 - k0n + 960 + t) * 16 + h] * LOG2E;
    if (t < 64) mask_s[d][t] = (mask[b * 1024 + k0n + t] == 0) ? -1.44e9f : 0.f;
  };

#pragma unroll
  for (int p = 0; p < 2; ++p)
    async16(&Pl[(p * 64 + w * 8) * 64],
            qkv + (size_t)(b * 1024 + q0 + p * 64 + w * 8 + srow) * 3072 + h * 64 + gc * 8);
  stage(0, kt0 * 64);
  __syncthreads();

  short8 qf[2];
#pragma unroll
  for (int kk = 0; kk < 2; ++kk)
    qf[kk] = *(const short8*)&Pl[qq * 64 + (((kk * 4 + lq) ^ (lm & 7)) << 3)];
  __syncthreads();

  float l_acc = 0.f;
  f32x4 acc_o[4];
#pragma unroll
  for (int j = 0; j < 4; ++j) acc_o[j] = (f32x4){0.f, 0.f, 0.f, 0.f};

  const float C0 = 0.125f * LOG2E;

  for (int kt = kt0; kt < kt0 + 8; ++kt) {
    const int d = kt & 1;
    if (kt + 1 < kt0 + 8) stage(d ^ 1, (kt + 1) * 64);

    f32x4 sa[4];
#pragma unroll
    for (int i = 0; i < 4; ++i) sa[i] = (f32x4){0.f, 0.f, 0.f, 0.f};
#pragma unroll
    for (int kk = 0; kk < 2; ++kk) {
      short8 ak[4];
#pragma unroll
      for (int mi = 0; mi < 4; ++mi) {
        int row = mi * 16 + lm;
        ak[mi] = *(const short8*)&Kl[d][row * 64 + (((kk * 4 + lq) ^ (lm & 7)) << 3)];
      }
#pragma unroll
      for (int mi = 0; mi < 4; ++mi)
        sa[mi] = __builtin_amdgcn_mfma_f32_16x16x32_bf16(ak[mi], qf[kk], sa[mi], 0, 0, 0);
    }

    float m4[4][4];
#pragma unroll
    for (int mi = 0; mi < 4; ++mi)
      *(float4*)m4[mi] = *(const float4*)&mask_s[d][mi * 16 + lq * 4];
#pragma unroll
    for (int mi = 0; mi < 4; ++mi)
#pragma unroll
      for (int r = 0; r < 4; ++r) {
        int kl = mi * 16 + lq * 4 + r;
        float p = __builtin_amdgcn_exp2f(
            fmaf(sa[mi][r], C0, bias_s[d][qq - kl + 63] + m4[mi][r]));
        sa[mi][r] = p;
        l_acc += p;
      }

#pragma unroll
    for (int mi = 0; mi < 4; ++mi) {
      bf16 h4[4];
#pragma unroll
      for (int r = 0; r < 4; ++r) h4[r] = __float2bfloat16(sa[mi][r]);
      int chunk = mi * 2 + (lq >> 1);
      *(uint2*)&Pl[qq * 64 + ((chunk ^ (lm & 7)) << 3) + ((lq & 1) << 2)] =
          *(uint2*)h4;
    }

#pragma unroll
    for (int kk2 = 0; kk2 < 2; ++kk2) {
      short8 pf = *(const short8*)&Pl[qq * 64 + (((kk2 * 4 + lq) ^ (lm & 7)) << 3)];
      short8 vf[4];
#pragma unroll
      for (int ni = 0; ni < 4; ++ni) {
        int rowv = ni * 16 + lm;
        vf[ni] = *(const short8*)&Vl[d][rowv * 64 + (((kk2 * 4 + lq) ^ (lm & 7)) << 3)];
      }
#pragma unroll
      for (int ni = 0; ni < 4; ++ni)
        acc_o[ni] = __builtin_amdgcn_mfma_f32_16x16x32_bf16(pf, vf[ni], acc_o[ni], 0, 0, 0);
    }
    __syncthreads();
  }

  // l_z for column qq (shared by the 4 lanes with equal lm)
  l_acc += __shfl_xor(l_acc, 16);
  l_acc += __shfl_xor(l_acc, 32);
  if (lq == 0)
    lpart[(size_t)z * 65536 + (size_t)bh * 1024 + q0 + qq] = l_acc;
  // unnormalized O_z
  bf16* cp = ctx_part + (size_t)z * 4194304;
#pragma unroll
  for (int r = 0; r < 4; ++r) {
    int qx = w * 16 + lq * 4 + r;
    size_t rowbase = (size_t)(b * 1024 + q0 + qx) * 1024 + h * 64;
#pragma unroll
    for (int ni = 0; ni < 4; ++ni)
      cp[rowbase + ni * 16 + lm] = __float2bfloat16(acc_o[ni][r]);
  }
}

// combine: ctx = (O0+O1)/(l0+l1)
__global__ __launch_bounds__(256) void combine_ctx(
    const bf16* __restrict__ part, const float* __restrict__ lpart,
    bf16* __restrict__ ctx) {
  const int row = blockIdx.x, t = threadIdx.x;
  const size_t base = (size_t)row * 1024 + t * 4;
  const int b = row >> 10, s = row & 1023;
  const int h = t >> 4;
  float lsum = lpart[(size_t)(b * 16 + h) * 1024 + s] +
               lpart[65536 + (size_t)(b * 16 + h) * 1024 + s];
  float inv = 1.f / lsum;
  ushort4 p0 = *(const ushort4*)((const unsigned short*)part + base);
  ushort4 p1 = *(const ushort4*)((const unsigned short*)part + 4194304 + base);
  bf16 h4[4] = {__float2bfloat16((bf2f(p0.x) + bf2f(p1.x)) * inv),
                __float2bfloat16((bf2f(p0.y) + bf2f(p1.y)) * inv),
                __float2bfloat16((bf2f(p0.z) + bf2f(p1.z)) * inv),
                __float2bfloat16((bf2f(p0.w) + bf2f(p1.w)) * inv)};
  *(uint2*)((unsigned short*)ctx + base) = *(uint2*)h4;
}

// ---------------- residual + split-K reduce + bias + layernorm ----------------

template <typename RT, int NS>
__global__ __launch_bounds__(256) void ln_resid(
    const RT* __restrict__ xin, const bf16* __restrict__ part,
    const float* __restrict__ bias,
    const float* __restrict__ gw, const float* __restrict__ bw,
    float* __restrict__ outf, bf16* __restrict__ outb) {
  const int row = blockIdx.x, t = threadIdx.x;
  const size_t base = (size_t)row * 1024 + t * 4;
  float v0, v1, v2, v3;
  if constexpr (sizeof(RT) == 4) {
    float4 xv = *(const float4*)(xin + base);
    v0 = xv.x; v1 = xv.y; v2 = xv.z; v3 = xv.w;
  } else {
    ushort4 xv = *(const ushort4*)((const unsigned short*)xin + base);
    v0 = bf2f(xv.x); v1 = bf2f(xv.y); v2 = bf2f(xv.z); v3 = bf2f(xv.w);
  }
  float4 bi = *(const float4*)(bias + t * 4);
  v0 += bi.x; v1 += bi.y; v2 += bi.z; v3 += bi.w;
#pragma unroll
  for (int s = 0; s < NS; ++s) {
    const bf16* p = part + (size_t)s * 4194304 + base;
    ushort4 pv = *(const ushort4*)p;
    v0 += bf2f(pv.x); v1 += bf2f(pv.y); v2 += bf2f(pv.z); v3 += bf2f(pv.w);
  }
  float s1 = v0 + v1 + v2 + v3;
  float s2 = v0 * v0 + v1 * v1 + v2 * v2 + v3 * v3;
#pragma unroll
  for (int o = 1; o < 64; o <<= 1) {
    s1 += __shfl_xor(s1, o);
    s2 += __shfl_xor(s2, o);
  }
  __shared__ float red[8];
  const int w = t >> 6, l = t & 63;
  if (l == 0) { red[w] = s1; red[4 + w] = s2; }
  __syncthreads();
  float S1 = red[0] + red[1] + red[2] + red[3];
  float S2 = red[4] + red[5] + red[6] + red[7];
  float mean = S1 * (1.f / 1024.f);
  float var = S2 * (1.f / 1024.f) - mean * mean;
  float rstd = rsqrtf(var + 1e-5f);
  float4 gv = *(const float4*)(gw + t * 4);
  float4 bv = *(const float4*)(bw + t * 4);
  float o0 = (v0 - mean) * rstd * gv.x + bv.x;
  float o1 = (v1 - mean) * rstd * gv.y + bv.y;
  float o2 = (v2 - mean) * rstd * gv.z + bv.z;
  float o3 = (v3 - mean) * rstd * gv.w + bv.w;
  if (outf) {
    float4 ov = {o0, o1, o2, o3};
    *(float4*)(outf + base) = ov;
  }
  if (outb) {
    bf16 h4[4] = {__float2bfloat16(o0), __float2bfloat16(o1),
                  __float2bfloat16(o2), __float2bfloat16(o3)};
    *(uint2*)((unsigned short*)outb + base) = *(uint2*)h4;
  }
}

// ---------------- launcher ----------------

extern "C" void kernel_launch(void* const* d_in, const int* in_sizes, int n_in,
                              void* d_out, int out_size, void* d_ws, size_t ws_size,
                              hipStream_t stream) {
  (void)in_sizes; (void)n_in; (void)out_size; (void)ws_size;
  const float* x   = (const float*)d_in[0];
  const float* wq  = (const float*)d_in[1];
  const float* bq  = (const float*)d_in[2];
  const float* wk  = (const float*)d_in[3];
  const float* bk  = (const float*)d_in[4];
  const float* wv  = (const float*)d_in[5];
  const float* bv  = (const float*)d_in[6];
  const float* wo  = (const float*)d_in[7];
  const float* bo  = (const float*)d_in[8];
  const float* rel = (const float*)d_in[9];
  const float* g1  = (const float*)d_in[10];
  const float* be1 = (const float*)d_in[11];
  const float* w1  = (const float*)d_in[12];
  const float* b1  = (const float*)d_in[13];
  const float* w2  = (const float*)d_in[14];
  const float* b2  = (const float*)d_in[15];
  const float* g2  = (const float*)d_in[16];
  const float* be2 = (const float*)d_in[17];
  const int* mask  = (const int*)d_in[18];
  float* out = (float*)d_out;

  char* ws = (char*)d_ws;
  bf16*  xb       = (bf16*)(ws + 0);
  bf16*  wqkv_t   = (bf16*)(ws + 8388608);
  bf16*  wo_t     = (bf16*)(ws + 14680064);
  bf16*  w1_t     = (bf16*)(ws + 16777216);
  bf16*  ctx_b    = (bf16*)(ws + 25165824);
  bf16*  x1b      = (bf16*)(ws + 33554432);
  float* lpart    = (float*)(ws + 33554432);   // aliases x1b (dead until ln1)
  bf16*  qkv_b    = (bf16*)(ws + 41943040);
  bf16*  vtb      = (bf16*)(ws + 67108864);
  bf16*  part_wo  = (bf16*)(ws + 41943040);    // aliases qkv_b+vtb (dead after flash)
  bf16*  h1       = (bf16*)(ws + 41943040);    // aliases qkv_b+vtb
  bf16*  part_ff  = (bf16*)(ws + 0);           // aliases xb..ctx_b (all dead by FFN2)
  bf16*  w2_t     = (bf16*)(ws + 75497472);
  bf16*  ctx_part = (bf16*)(ws + 83886080);    // old x1f region, 2 x 8.4 MB
  float* bqkv     = (float*)(ws + 100663296);

  prep_all<<<16385, 256, 0, stream>>>(x, bq, bk, bv, wq, wk, wv, wo, w1, w2,
                                      xb, bqkv, wqkv_t, wo_t, w1_t, w2_t);

  // QKV (+ fused V-transpose into vtb)
  gemm_bt<0, 1><<<dim3(32, 24), 256, 0, stream>>>(
      xb, wqkv_t, bqkv, qkv_b, vtb, 4096, 3072, 1024);
  // flash split-S=2: unnormalized partials, then combine
  flash_attn<<<dim3(8, 64, 2), 512, 0, stream>>>(
      qkv_b, vtb, rel, mask, ctx_part, lpart);
  combine_ctx<<<4096, 256, 0, stream>>>(ctx_part, lpart, ctx_b);
  // WO: split-K=2 (512 blocks), KS=512
  gemm_bt_splitk<<<dim3(32, 8, 2), 256, 0, stream>>>(
      ctx_b, wo_t, part_wo, 4096, 1024, 1024, 512);
  ln_resid<float, 2><<<4096, 256, 0, stream>>>(x, part_wo, bo, g1, be1, nullptr, x1b);
  gemm_bt<1, 0><<<dim3(32, 32), 256, 0, stream>>>(
      x1b, w1_t, b1, h1, nullptr, 4096, 4096, 1024);
  // FFN2: split-K=2 (512 blocks), KS=2048
  gemm_bt_splitk<<<dim3(32, 8, 2), 256, 0, stream>>>(
      h1, w2_t, part_ff, 4096, 1024, 4096, 2048);
  ln_resid<bf16, 2><<<4096, 256, 0, stream>>>(x1b, part_ff, b2, g2, be2, out, nullptr);
}